// Round 2
// baseline (1103.053 us; speedup 1.0000x reference)
//
#include <hip/hip_runtime.h>

#define NFEAT 64

// ---------------- degree kernels ----------------
__global__ void k_init_deg(float* deg, int n) {
    int i = blockIdx.x * 256 + threadIdx.x;
    if (i < n) deg[i] = 1.0f;  // self-loop
}

__global__ void k_count_deg(const int* __restrict__ ei, float* deg, int E) {
    int e = blockIdx.x * 256 + threadIdx.x;
    if (e < E) atomicAdd(&deg[ei[(size_t)E + e]], 1.0f);
}

__global__ void k_rsqrt(float* deg, int n) {
    int i = blockIdx.x * 256 + threadIdx.x;
    if (i < n) deg[i] = rsqrtf(deg[i]);
}

// ---------------- fused GEMM: H = act(A) @ W ; OUT = bias + dinv^2 * H ----------------
// A: [M x K] row-major, W: [K x 64] row-major, H/OUT: [M x 64]
template<int K, bool RELU>
__global__ __launch_bounds__(256) void k_gemm_fused(
    const float* __restrict__ A, const float* __restrict__ W,
    const float* __restrict__ bias, const float* __restrict__ dinv,
    float* __restrict__ H, float* __restrict__ OUT, int M)
{
    const int BM = 128, BK = 32;
    __shared__ float As[BM][BK + 1];   // +1 pad: conflict-free scalar access
    __shared__ float Ws[BK][NFEAT];

    int tid = threadIdx.x;
    int tx = tid & 15;   // col group: cols 4*tx .. 4*tx+3
    int ty = tid >> 4;   // row group: rows 8*ty .. 8*ty+7
    int m0 = blockIdx.x * BM;

    float acc[8][4];
#pragma unroll
    for (int i = 0; i < 8; ++i)
#pragma unroll
        for (int j = 0; j < 4; ++j) acc[i][j] = 0.f;

    for (int k0 = 0; k0 < K; k0 += BK) {
        // stage A tile: 128 rows x 32 k = 1024 float4, 4 per thread
#pragma unroll
        for (int rep = 0; rep < 4; ++rep) {
            int s = tid + rep * 256;        // 0..1023
            int m = s >> 3;                 // 0..127
            int kk = (s & 7) << 2;          // 0,4,...,28
            int row = m0 + m;
            float4 a = make_float4(0.f, 0.f, 0.f, 0.f);
            if (row < M) {
                a = *(const float4*)(A + (size_t)row * K + k0 + kk);
                if (RELU) {
                    a.x = fmaxf(a.x, 0.f); a.y = fmaxf(a.y, 0.f);
                    a.z = fmaxf(a.z, 0.f); a.w = fmaxf(a.w, 0.f);
                }
            }
            As[m][kk + 0] = a.x; As[m][kk + 1] = a.y;
            As[m][kk + 2] = a.z; As[m][kk + 3] = a.w;
        }
        // stage W tile: 32 x 64 = 512 float4, 2 per thread
#pragma unroll
        for (int rep = 0; rep < 2; ++rep) {
            int s = tid + rep * 256;        // 0..511
            int kk = s >> 4;                // 0..31
            int n = (s & 15) << 2;          // 0..60
            *(float4*)&Ws[kk][n] = *(const float4*)(W + (size_t)(k0 + kk) * NFEAT + n);
        }
        __syncthreads();
#pragma unroll
        for (int k = 0; k < BK; ++k) {
            float w0 = Ws[k][tx * 4 + 0];
            float w1 = Ws[k][tx * 4 + 1];
            float w2 = Ws[k][tx * 4 + 2];
            float w3 = Ws[k][tx * 4 + 3];
#pragma unroll
            for (int i = 0; i < 8; ++i) {
                float av = As[ty * 8 + i][k];
                acc[i][0] = fmaf(av, w0, acc[i][0]);
                acc[i][1] = fmaf(av, w1, acc[i][1]);
                acc[i][2] = fmaf(av, w2, acc[i][2]);
                acc[i][3] = fmaf(av, w3, acc[i][3]);
            }
        }
        __syncthreads();
    }

    // epilogue: write H and OUT = bias + dinv^2 * H (self-loop + bias pre-init)
    float b0 = bias[tx * 4 + 0], b1 = bias[tx * 4 + 1];
    float b2 = bias[tx * 4 + 2], b3 = bias[tx * 4 + 3];
#pragma unroll
    for (int i = 0; i < 8; ++i) {
        int row = m0 + ty * 8 + i;
        if (row < M) {
            float di = dinv[row];
            float dd = di * di;
            float4 h4 = make_float4(acc[i][0], acc[i][1], acc[i][2], acc[i][3]);
            *(float4*)(H + (size_t)row * NFEAT + tx * 4) = h4;
            float4 o4 = make_float4(b0 + dd * h4.x, b1 + dd * h4.y,
                                    b2 + dd * h4.z, b3 + dd * h4.w);
            *(float4*)(OUT + (size_t)row * NFEAT + tx * 4) = o4;
        }
    }
}

// ---------------- edge scatter: one wave per edge, lane = feature ----------------
__global__ __launch_bounds__(256) void k_scatter(
    const float* __restrict__ h, float* __restrict__ out,
    const int* __restrict__ ei, const float* __restrict__ dinv, int E)
{
    int e = (blockIdx.x << 2) + (threadIdx.x >> 6);
    if (e >= E) return;
    int lane = threadIdx.x & 63;
    int src = ei[e];
    int dst = ei[(size_t)E + e];
    float nrm = dinv[src] * dinv[dst];
    float v = nrm * h[(size_t)src * NFEAT + lane];
    atomicAdd(out + (size_t)dst * NFEAT + lane, v);
}

// ---------------- final FC: out[r][c] = relu(A[r]) . Wfc[:,c] + bfc[c] ----------------
__global__ __launch_bounds__(256) void k_fc(
    const float* __restrict__ A, const float* __restrict__ Wfc,
    const float* __restrict__ bfc, float* __restrict__ out, int M)
{
    __shared__ float Wl[NFEAT * 11];
    __shared__ float bl[11];
    int tid = threadIdx.x;
    for (int i = tid; i < NFEAT * 11; i += 256) Wl[i] = Wfc[i];
    if (tid < 11) bl[tid] = bfc[tid];
    __syncthreads();

    int lane = tid & 63;
    int r = blockIdx.x * 4 + (tid >> 6);
    if (r >= M) return;

    float v = fmaxf(A[(size_t)r * NFEAT + lane], 0.f);
    float res = 0.f;
#pragma unroll
    for (int c = 0; c < 11; ++c) {
        float p = v * Wl[lane * 11 + c];
#pragma unroll
        for (int off = 32; off; off >>= 1) p += __shfl_xor(p, off, 64);
        if (lane == c) res = p + bl[c];
    }
    if (lane < 11) out[(size_t)r * 11 + lane] = res;
}

extern "C" void kernel_launch(void* const* d_in, const int* in_sizes, int n_in,
                              void* d_out, int out_size, void* d_ws, size_t ws_size,
                              hipStream_t stream) {
    const float* x   = (const float*)d_in[0];
    const int*   ei  = (const int*)d_in[1];    // harness delivers integer inputs as int32
    const float* W1  = (const float*)d_in[2];
    const float* b1  = (const float*)d_in[3];
    const float* W2  = (const float*)d_in[4];
    const float* b2  = (const float*)d_in[5];
    const float* Wfc = (const float*)d_in[6];
    const float* bfc = (const float*)d_in[7];
    float* out = (float*)d_out;

    const int Fin = 256;
    int N = in_sizes[0] / Fin;      // 100000
    int E = in_sizes[1] / 2;        // 1600000

    char* ws = (char*)d_ws;
    float* dinv = (float*)ws;
    size_t offA = ((size_t)N * 4 + 255) & ~(size_t)255;
    float* A = (float*)(ws + offA);                     // h buffer  [N x 64]
    size_t offB = offA + ((((size_t)N * NFEAT * 4) + 255) & ~(size_t)255);
    float* B = (float*)(ws + offB);                     // out buffer [N x 64]

    int gN = (N + 255) / 256;
    int gE = (E + 255) / 256;
    int gb = (N + 127) / 128;
    int gS = (E + 3) / 4;

    // degrees -> dinv
    k_init_deg<<<gN, 256, 0, stream>>>(dinv, N);
    k_count_deg<<<gE, 256, 0, stream>>>(ei, dinv, E);
    k_rsqrt<<<gN, 256, 0, stream>>>(dinv, N);

    // layer 1: h1 = x@W1 (A), out1 = b1 + dinv^2*h1 (B), then scatter edges into B
    k_gemm_fused<256, false><<<gb, 256, 0, stream>>>(x, W1, b1, dinv, A, B, N);
    k_scatter<<<gS, 256, 0, stream>>>(A, B, ei, dinv, E);

    // layer 2: h2 = relu(out1)@W2 (A), out2 = b2 + dinv^2*h2 (B in-place: row-local)
    k_gemm_fused<64, true><<<gb, 256, 0, stream>>>(B, W2, b2, dinv, A, B, N);
    k_scatter<<<gS, 256, 0, stream>>>(A, B, ei, dinv, E);

    // final FC: out = relu(out2)@Wfc + bfc
    k_fc<<<(N + 3) / 4, 256, 0, stream>>>(B, Wfc, bfc, out, N);
}

// Round 3
// 640.323 us; speedup vs baseline: 1.7227x; 1.7227x over previous
//
#include <hip/hip_runtime.h>

#define NFEAT 64
#define SCAN_CHUNK 2048   // 256 threads x 8

// ---------------- degree / CSR build ----------------
__global__ void k_zero(int* p, int n) {
    int i = blockIdx.x * 256 + threadIdx.x;
    if (i < n) p[i] = 0;
}

__global__ void k_count(const int* __restrict__ ei, int* counts, int E) {
    int e = blockIdx.x * 256 + threadIdx.x;
    if (e < E) atomicAdd(&counts[ei[(size_t)E + e]], 1);
}

__global__ void k_dinv(const int* __restrict__ counts, float* dinv, int n) {
    int i = blockIdx.x * 256 + threadIdx.x;
    if (i < n) dinv[i] = rsqrtf((float)(counts[i] + 1));  // +1 self-loop
}

// phase A: per-block reduce of counts
__global__ __launch_bounds__(256) void k_scan_block(const int* __restrict__ counts,
                                                    int* __restrict__ bsums, int n) {
    __shared__ int red[256];
    int tid = threadIdx.x;
    int base = blockIdx.x * SCAN_CHUNK + tid * 8;
    int s = 0;
#pragma unroll
    for (int i = 0; i < 8; ++i) {
        int idx = base + i;
        s += (idx < n) ? counts[idx] : 0;
    }
    red[tid] = s;
    __syncthreads();
    for (int off = 128; off; off >>= 1) {
        if (tid < off) red[tid] += red[tid + off];
        __syncthreads();
    }
    if (tid == 0) bsums[blockIdx.x] = red[0];
}

// phase B: exclusive scan of block sums (nb <= 64), single block
__global__ void k_scan_sums(int* bsums, int nb) {
    __shared__ int ts[64];
    int tid = threadIdx.x;
    if (tid < 64) ts[tid] = (tid < nb) ? bsums[tid] : 0;
    __syncthreads();
    if (tid == 0) {
        int run = 0;
        for (int i = 0; i < nb; ++i) { int t = ts[i]; ts[i] = run; run += t; }
    }
    __syncthreads();
    if (tid < nb) bsums[tid] = ts[tid];
}

// phase C: full exclusive scan -> rowptr (and cursor copy); rowptr[n]=E
__global__ __launch_bounds__(256) void k_scan_final(const int* __restrict__ counts,
                                                    const int* __restrict__ bsums,
                                                    int* __restrict__ rowptr,
                                                    int* __restrict__ cursor, int n) {
    __shared__ int ts[256];
    int tid = threadIdx.x;
    int base0 = blockIdx.x * SCAN_CHUNK + tid * 8;
    int v[8], c[8];
    int s = 0;
#pragma unroll
    for (int i = 0; i < 8; ++i) {
        int idx = base0 + i;
        c[i] = (idx < n) ? counts[idx] : 0;
        v[i] = s;
        s += c[i];
    }
    ts[tid] = s;
    __syncthreads();
    // Hillis-Steele inclusive scan over thread sums
    for (int off = 1; off < 256; off <<= 1) {
        int t = (tid >= off) ? ts[tid - off] : 0;
        __syncthreads();
        if (tid >= off) ts[tid] += t;
        __syncthreads();
    }
    int texcl = ts[tid] - s;                 // exclusive thread offset
    int base = bsums[blockIdx.x] + texcl;
#pragma unroll
    for (int i = 0; i < 8; ++i) {
        int idx = base0 + i;
        if (idx < n) {
            int val = base + v[i];
            rowptr[idx] = val;
            cursor[idx] = val;
            if (idx == n - 1) rowptr[n] = val + c[i];
        }
    }
}

// placement: col[p]=src, wgt[p]=dinv[src]
__global__ void k_build(const int* __restrict__ ei, int* __restrict__ cursor,
                        int* __restrict__ col, float* __restrict__ wgt,
                        const float* __restrict__ dinv, int E) {
    int e = blockIdx.x * 256 + threadIdx.x;
    if (e >= E) return;
    int src = ei[e];
    int dst = ei[(size_t)E + e];
    int p = atomicAdd(&cursor[dst], 1);
    col[p] = src;
    wgt[p] = dinv[src];
}

// ---------------- GEMM: H = act(A) @ W ----------------
template<int K, bool RELU>
__global__ __launch_bounds__(256) void k_gemm(
    const float* __restrict__ A, const float* __restrict__ W,
    float* __restrict__ H, int M)
{
    const int BM = 128, BK = 32;
    __shared__ float As[BM][BK + 1];
    __shared__ float Ws[BK][NFEAT];

    int tid = threadIdx.x;
    int tx = tid & 15;
    int ty = tid >> 4;
    int m0 = blockIdx.x * BM;

    float acc[8][4];
#pragma unroll
    for (int i = 0; i < 8; ++i)
#pragma unroll
        for (int j = 0; j < 4; ++j) acc[i][j] = 0.f;

    for (int k0 = 0; k0 < K; k0 += BK) {
#pragma unroll
        for (int rep = 0; rep < 4; ++rep) {
            int s = tid + rep * 256;
            int m = s >> 3;
            int kk = (s & 7) << 2;
            int row = m0 + m;
            float4 a = make_float4(0.f, 0.f, 0.f, 0.f);
            if (row < M) {
                a = *(const float4*)(A + (size_t)row * K + k0 + kk);
                if (RELU) {
                    a.x = fmaxf(a.x, 0.f); a.y = fmaxf(a.y, 0.f);
                    a.z = fmaxf(a.z, 0.f); a.w = fmaxf(a.w, 0.f);
                }
            }
            As[m][kk + 0] = a.x; As[m][kk + 1] = a.y;
            As[m][kk + 2] = a.z; As[m][kk + 3] = a.w;
        }
#pragma unroll
        for (int rep = 0; rep < 2; ++rep) {
            int s = tid + rep * 256;
            int kk = s >> 4;
            int n = (s & 15) << 2;
            *(float4*)&Ws[kk][n] = *(const float4*)(W + (size_t)(k0 + kk) * NFEAT + n);
        }
        __syncthreads();
#pragma unroll
        for (int k = 0; k < BK; ++k) {
            float w0 = Ws[k][tx * 4 + 0];
            float w1 = Ws[k][tx * 4 + 1];
            float w2 = Ws[k][tx * 4 + 2];
            float w3 = Ws[k][tx * 4 + 3];
#pragma unroll
            for (int i = 0; i < 8; ++i) {
                float av = As[ty * 8 + i][k];
                acc[i][0] = fmaf(av, w0, acc[i][0]);
                acc[i][1] = fmaf(av, w1, acc[i][1]);
                acc[i][2] = fmaf(av, w2, acc[i][2]);
                acc[i][3] = fmaf(av, w3, acc[i][3]);
            }
        }
        __syncthreads();
    }

#pragma unroll
    for (int i = 0; i < 8; ++i) {
        int row = m0 + ty * 8 + i;
        if (row < M) {
            float4 h4 = make_float4(acc[i][0], acc[i][1], acc[i][2], acc[i][3]);
            *(float4*)(H + (size_t)row * NFEAT + tx * 4) = h4;
        }
    }
}

// ---------------- CSR gather-aggregate ----------------
// out[r] = bias + dinv[r] * ( dinv[r]*h[r] + sum_j wgt[j]*h[col[j]] )
__global__ __launch_bounds__(256) void k_aggr(
    const float* __restrict__ h, const int* __restrict__ rowptr,
    const int* __restrict__ col, const float* __restrict__ wgt,
    const float* __restrict__ dinv, const float* __restrict__ bias,
    float* __restrict__ out, int n)
{
    int lane = threadIdx.x & 63;
    int r = blockIdx.x * 4 + (threadIdx.x >> 6);
    if (r >= n) return;
    int beg = rowptr[r], end = rowptr[r + 1];
    float di = dinv[r];
    float acc = di * h[(size_t)r * NFEAT + lane];   // self-loop term
    int j = beg;
    for (; j + 3 < end; j += 4) {
        int c0 = col[j], c1 = col[j + 1], c2 = col[j + 2], c3 = col[j + 3];
        float w0 = wgt[j], w1 = wgt[j + 1], w2 = wgt[j + 2], w3 = wgt[j + 3];
        float h0 = h[(size_t)c0 * NFEAT + lane];
        float h1 = h[(size_t)c1 * NFEAT + lane];
        float h2 = h[(size_t)c2 * NFEAT + lane];
        float h3 = h[(size_t)c3 * NFEAT + lane];
        acc = fmaf(w0, h0, acc); acc = fmaf(w1, h1, acc);
        acc = fmaf(w2, h2, acc); acc = fmaf(w3, h3, acc);
    }
    for (; j < end; ++j) acc = fmaf(wgt[j], h[(size_t)col[j] * NFEAT + lane], acc);
    out[(size_t)r * NFEAT + lane] = bias[lane] + di * acc;
}

// ---------------- final FC ----------------
__global__ __launch_bounds__(256) void k_fc(
    const float* __restrict__ A, const float* __restrict__ Wfc,
    const float* __restrict__ bfc, float* __restrict__ out, int M)
{
    __shared__ float Wl[NFEAT * 11];
    __shared__ float bl[11];
    int tid = threadIdx.x;
    for (int i = tid; i < NFEAT * 11; i += 256) Wl[i] = Wfc[i];
    if (tid < 11) bl[tid] = bfc[tid];
    __syncthreads();

    int lane = tid & 63;
    int r = blockIdx.x * 4 + (tid >> 6);
    if (r >= M) return;

    float v = fmaxf(A[(size_t)r * NFEAT + lane], 0.f);
    float res = 0.f;
#pragma unroll
    for (int c = 0; c < 11; ++c) {
        float p = v * Wl[lane * 11 + c];
#pragma unroll
        for (int off = 32; off; off >>= 1) p += __shfl_xor(p, off, 64);
        if (lane == c) res = p + bl[c];
    }
    if (lane < 11) out[(size_t)r * 11 + lane] = res;
}

extern "C" void kernel_launch(void* const* d_in, const int* in_sizes, int n_in,
                              void* d_out, int out_size, void* d_ws, size_t ws_size,
                              hipStream_t stream) {
    const float* x   = (const float*)d_in[0];
    const int*   ei  = (const int*)d_in[1];
    const float* W1  = (const float*)d_in[2];
    const float* b1  = (const float*)d_in[3];
    const float* W2  = (const float*)d_in[4];
    const float* b2  = (const float*)d_in[5];
    const float* Wfc = (const float*)d_in[6];
    const float* bfc = (const float*)d_in[7];
    float* out = (float*)d_out;

    const int Fin = 256;
    int N = in_sizes[0] / Fin;      // 100000
    int E = in_sizes[1] / 2;        // 1600000

    // workspace layout
    char* ws = (char*)d_ws;
    size_t off = 0;
    auto alloc = [&](size_t bytes) { void* p = ws + off; off = (off + bytes + 255) & ~(size_t)255; return p; };
    int*   counts = (int*)  alloc((size_t)N * 4);
    int*   rowptr = (int*)  alloc((size_t)(N + 1) * 4);
    int*   cursor = (int*)  alloc((size_t)N * 4);
    float* dinv   = (float*)alloc((size_t)N * 4);
    int*   bsums  = (int*)  alloc(64 * 4);
    int*   col    = (int*)  alloc((size_t)E * 4);
    float* wgt    = (float*)alloc((size_t)E * 4);
    float* A      = (float*)alloc((size_t)N * NFEAT * 4);  // h buffer
    float* B      = (float*)alloc((size_t)N * NFEAT * 4);  // out buffer

    int gN = (N + 255) / 256;
    int gE = (E + 255) / 256;
    int gb = (N + 127) / 128;
    int gA = (N + 3) / 4;
    int nb = (N + SCAN_CHUNK - 1) / SCAN_CHUNK;   // 49 <= 64

    // CSR build
    k_zero<<<gN, 256, 0, stream>>>(counts, N);
    k_count<<<gE, 256, 0, stream>>>(ei, counts, E);
    k_dinv<<<gN, 256, 0, stream>>>(counts, dinv, N);
    k_scan_block<<<nb, 256, 0, stream>>>(counts, bsums, N);
    k_scan_sums<<<1, 64, 0, stream>>>(bsums, nb);
    k_scan_final<<<nb, 256, 0, stream>>>(counts, bsums, rowptr, cursor, N);
    k_build<<<gE, 256, 0, stream>>>(ei, cursor, col, wgt, dinv, E);

    // layer 1
    k_gemm<256, false><<<gb, 256, 0, stream>>>(x, W1, A, N);
    k_aggr<<<gA, 256, 0, stream>>>(A, rowptr, col, wgt, dinv, b1, B, N);

    // layer 2 (relu fused on GEMM load)
    k_gemm<64, true><<<gb, 256, 0, stream>>>(B, W2, A, N);
    k_aggr<<<gA, 256, 0, stream>>>(A, rowptr, col, wgt, dinv, b2, B, N);

    // final FC
    k_fc<<<gA, 256, 0, stream>>>(B, Wfc, bfc, out, N);
}

// Round 4
// 576.971 us; speedup vs baseline: 1.9118x; 1.1098x over previous
//
#include <hip/hip_runtime.h>

#define NFEAT 64
#define SCAN_CHUNK 2048   // 256 threads x 8

// ---------------- degree / CSR build ----------------
__global__ void k_zero(int* p, int n) {
    int i = blockIdx.x * 256 + threadIdx.x;
    if (i < n) p[i] = 0;
}

// count in-degree AND capture each edge's rank within its dst bucket
__global__ void k_count(const int* __restrict__ ei, int* __restrict__ counts,
                        int* __restrict__ rank, int E) {
    int e = blockIdx.x * 256 + threadIdx.x;
    if (e < E) rank[e] = atomicAdd(&counts[ei[(size_t)E + e]], 1);
}

__global__ void k_dinv(const int* __restrict__ counts, float* dinv, int n) {
    int i = blockIdx.x * 256 + threadIdx.x;
    if (i < n) dinv[i] = rsqrtf((float)(counts[i] + 1));  // +1 self-loop
}

// phase A: per-block reduce of counts
__global__ __launch_bounds__(256) void k_scan_block(const int* __restrict__ counts,
                                                    int* __restrict__ bsums, int n) {
    __shared__ int red[256];
    int tid = threadIdx.x;
    int base = blockIdx.x * SCAN_CHUNK + tid * 8;
    int s = 0;
#pragma unroll
    for (int i = 0; i < 8; ++i) {
        int idx = base + i;
        s += (idx < n) ? counts[idx] : 0;
    }
    red[tid] = s;
    __syncthreads();
    for (int off = 128; off; off >>= 1) {
        if (tid < off) red[tid] += red[tid + off];
        __syncthreads();
    }
    if (tid == 0) bsums[blockIdx.x] = red[0];
}

// phase B: exclusive scan of block sums (nb <= 64), single block
__global__ void k_scan_sums(int* bsums, int nb) {
    __shared__ int ts[64];
    int tid = threadIdx.x;
    if (tid < 64) ts[tid] = (tid < nb) ? bsums[tid] : 0;
    __syncthreads();
    if (tid == 0) {
        int run = 0;
        for (int i = 0; i < nb; ++i) { int t = ts[i]; ts[i] = run; run += t; }
    }
    __syncthreads();
    if (tid < nb) bsums[tid] = ts[tid];
}

// phase C: full exclusive scan -> rowptr; rowptr[n]=E
__global__ __launch_bounds__(256) void k_scan_final(const int* __restrict__ counts,
                                                    const int* __restrict__ bsums,
                                                    int* __restrict__ rowptr, int n) {
    __shared__ int ts[256];
    int tid = threadIdx.x;
    int base0 = blockIdx.x * SCAN_CHUNK + tid * 8;
    int v[8], c[8];
    int s = 0;
#pragma unroll
    for (int i = 0; i < 8; ++i) {
        int idx = base0 + i;
        c[i] = (idx < n) ? counts[idx] : 0;
        v[i] = s;
        s += c[i];
    }
    ts[tid] = s;
    __syncthreads();
    for (int off = 1; off < 256; off <<= 1) {
        int t = (tid >= off) ? ts[tid - off] : 0;
        __syncthreads();
        if (tid >= off) ts[tid] += t;
        __syncthreads();
    }
    int texcl = ts[tid] - s;
    int base = bsums[blockIdx.x] + texcl;
#pragma unroll
    for (int i = 0; i < 8; ++i) {
        int idx = base0 + i;
        if (idx < n) {
            int val = base + v[i];
            rowptr[idx] = val;
            if (idx == n - 1) rowptr[n] = val + c[i];
        }
    }
}

// placement, atomic-free: col[rowptr[dst]+rank[e]] = src
__global__ void k_build(const int* __restrict__ ei, const int* __restrict__ rank,
                        const int* __restrict__ rowptr, int* __restrict__ col, int E) {
    int e = blockIdx.x * 256 + threadIdx.x;
    if (e >= E) return;
    int src = ei[e];
    int dst = ei[(size_t)E + e];
    col[rowptr[dst] + rank[e]] = src;
}

// ---------------- GEMM: H = dinv * (act(A) @ W) ----------------
// LDS-vectorized: float4 (ds_read_b128) fragment loads, conflict-free row mapping.
template<int K, bool RELU>
__global__ __launch_bounds__(256) void k_gemm(
    const float* __restrict__ A, const float* __restrict__ W,
    const float* __restrict__ dinv, float* __restrict__ H, int M)
{
    const int BM = 128, BK = 32;
    const int ASTR = BK + 4;      // 36 floats: float4-aligned, rows 4 banks apart
    const int WSTR = NFEAT + 4;   // 68 floats
    __shared__ float As[BM * ASTR];
    __shared__ float Ws[BK * WSTR];

    int tid = threadIdx.x;
    int tx = tid & 15;    // col quad: cols 4*tx..4*tx+3
    int ty = tid >> 4;    // 0..15; thread's rows are i*16+ty, i=0..7
    int m0 = blockIdx.x * BM;

    float4 acc[8];
#pragma unroll
    for (int i = 0; i < 8; ++i) acc[i] = make_float4(0.f, 0.f, 0.f, 0.f);

    for (int k0 = 0; k0 < K; k0 += BK) {
        // stage A tile: 128 rows x 32 k = 1024 float4
#pragma unroll
        for (int rep = 0; rep < 4; ++rep) {
            int s = tid + rep * 256;
            int m = s >> 3;
            int kk = (s & 7) << 2;
            int row = m0 + m;
            float4 a = make_float4(0.f, 0.f, 0.f, 0.f);
            if (row < M) {
                a = *(const float4*)(A + (size_t)row * K + k0 + kk);
                if (RELU) {
                    a.x = fmaxf(a.x, 0.f); a.y = fmaxf(a.y, 0.f);
                    a.z = fmaxf(a.z, 0.f); a.w = fmaxf(a.w, 0.f);
                }
            }
            *(float4*)&As[m * ASTR + kk] = a;
        }
        // stage W tile: 32 x 64
#pragma unroll
        for (int rep = 0; rep < 2; ++rep) {
            int s = tid + rep * 256;
            int kk = s >> 4;
            int n = (s & 15) << 2;
            *(float4*)&Ws[kk * WSTR + n] = *(const float4*)(W + (size_t)(k0 + kk) * NFEAT + n);
        }
        __syncthreads();
#pragma unroll
        for (int kg = 0; kg < BK; kg += 4) {
            float4 w0 = *(const float4*)&Ws[(kg + 0) * WSTR + tx * 4];
            float4 w1 = *(const float4*)&Ws[(kg + 1) * WSTR + tx * 4];
            float4 w2 = *(const float4*)&Ws[(kg + 2) * WSTR + tx * 4];
            float4 w3 = *(const float4*)&Ws[(kg + 3) * WSTR + tx * 4];
#pragma unroll
            for (int i = 0; i < 8; ++i) {
                float4 a = *(const float4*)&As[(i * 16 + ty) * ASTR + kg];
                acc[i].x = fmaf(a.x, w0.x, acc[i].x);
                acc[i].y = fmaf(a.x, w0.y, acc[i].y);
                acc[i].z = fmaf(a.x, w0.z, acc[i].z);
                acc[i].w = fmaf(a.x, w0.w, acc[i].w);
                acc[i].x = fmaf(a.y, w1.x, acc[i].x);
                acc[i].y = fmaf(a.y, w1.y, acc[i].y);
                acc[i].z = fmaf(a.y, w1.z, acc[i].z);
                acc[i].w = fmaf(a.y, w1.w, acc[i].w);
                acc[i].x = fmaf(a.z, w2.x, acc[i].x);
                acc[i].y = fmaf(a.z, w2.y, acc[i].y);
                acc[i].z = fmaf(a.z, w2.z, acc[i].z);
                acc[i].w = fmaf(a.z, w2.w, acc[i].w);
                acc[i].x = fmaf(a.w, w3.x, acc[i].x);
                acc[i].y = fmaf(a.w, w3.y, acc[i].y);
                acc[i].z = fmaf(a.w, w3.z, acc[i].z);
                acc[i].w = fmaf(a.w, w3.w, acc[i].w);
            }
        }
        __syncthreads();
    }

    // epilogue: H = dinv[row] * acc   (pre-scale so aggregation is unweighted)
#pragma unroll
    for (int i = 0; i < 8; ++i) {
        int row = m0 + i * 16 + ty;
        if (row < M) {
            float di = dinv[row];
            float4 h4 = make_float4(di * acc[i].x, di * acc[i].y,
                                    di * acc[i].z, di * acc[i].w);
            *(float4*)(H + (size_t)row * NFEAT + tx * 4) = h4;
        }
    }
}

// ---------------- CSR gather-aggregate (unweighted: h is pre-scaled by dinv) ----
// out[r] = bias + dinv[r] * ( h[r] + sum_j h[col[j]] )
__global__ __launch_bounds__(256) void k_aggr(
    const float* __restrict__ h, const int* __restrict__ rowptr,
    const int* __restrict__ col, const float* __restrict__ dinv,
    const float* __restrict__ bias, float* __restrict__ out, int n)
{
    int lane = threadIdx.x & 63;
    int r = blockIdx.x * 4 + (threadIdx.x >> 6);
    if (r >= n) return;
    int beg = rowptr[r], end = rowptr[r + 1];
    float acc = h[(size_t)r * NFEAT + lane];   // self-loop term
    int j = beg;
    for (; j + 3 < end; j += 4) {
        int c0 = col[j], c1 = col[j + 1], c2 = col[j + 2], c3 = col[j + 3];
        acc += h[(size_t)c0 * NFEAT + lane];
        acc += h[(size_t)c1 * NFEAT + lane];
        acc += h[(size_t)c2 * NFEAT + lane];
        acc += h[(size_t)c3 * NFEAT + lane];
    }
    for (; j < end; ++j) acc += h[(size_t)col[j] * NFEAT + lane];
    out[(size_t)r * NFEAT + lane] = bias[lane] + dinv[r] * acc;
}

// ---------------- final FC ----------------
__global__ __launch_bounds__(256) void k_fc(
    const float* __restrict__ A, const float* __restrict__ Wfc,
    const float* __restrict__ bfc, float* __restrict__ out, int M)
{
    __shared__ float Wl[NFEAT * 11];
    __shared__ float bl[11];
    int tid = threadIdx.x;
    for (int i = tid; i < NFEAT * 11; i += 256) Wl[i] = Wfc[i];
    if (tid < 11) bl[tid] = bfc[tid];
    __syncthreads();

    int lane = tid & 63;
    int r = blockIdx.x * 4 + (tid >> 6);
    if (r >= M) return;

    float v = fmaxf(A[(size_t)r * NFEAT + lane], 0.f);
    float res = 0.f;
#pragma unroll
    for (int c = 0; c < 11; ++c) {
        float p = v * Wl[lane * 11 + c];
#pragma unroll
        for (int off = 32; off; off >>= 1) p += __shfl_xor(p, off, 64);
        if (lane == c) res = p + bl[c];
    }
    if (lane < 11) out[(size_t)r * 11 + lane] = res;
}

extern "C" void kernel_launch(void* const* d_in, const int* in_sizes, int n_in,
                              void* d_out, int out_size, void* d_ws, size_t ws_size,
                              hipStream_t stream) {
    const float* x   = (const float*)d_in[0];
    const int*   ei  = (const int*)d_in[1];
    const float* W1  = (const float*)d_in[2];
    const float* b1  = (const float*)d_in[3];
    const float* W2  = (const float*)d_in[4];
    const float* b2  = (const float*)d_in[5];
    const float* Wfc = (const float*)d_in[6];
    const float* bfc = (const float*)d_in[7];
    float* out = (float*)d_out;

    const int Fin = 256;
    int N = in_sizes[0] / Fin;      // 100000
    int E = in_sizes[1] / 2;        // 1600000

    char* ws = (char*)d_ws;
    size_t off = 0;
    auto alloc = [&](size_t bytes) { void* p = ws + off; off = (off + bytes + 255) & ~(size_t)255; return p; };
    int*   counts = (int*)  alloc((size_t)N * 4);
    int*   rowptr = (int*)  alloc((size_t)(N + 1) * 4);
    float* dinv   = (float*)alloc((size_t)N * 4);
    int*   bsums  = (int*)  alloc(64 * 4);
    int*   rank   = (int*)  alloc((size_t)E * 4);
    int*   col    = (int*)  alloc((size_t)E * 4);
    float* A      = (float*)alloc((size_t)N * NFEAT * 4);  // h buffer
    float* B      = (float*)alloc((size_t)N * NFEAT * 4);  // out buffer

    int gN = (N + 255) / 256;
    int gE = (E + 255) / 256;
    int gb = (N + 127) / 128;
    int gA = (N + 3) / 4;
    int nb = (N + SCAN_CHUNK - 1) / SCAN_CHUNK;   // 49 <= 64

    // CSR build (atomic-free placement via ranks)
    k_zero<<<gN, 256, 0, stream>>>(counts, N);
    k_count<<<gE, 256, 0, stream>>>(ei, counts, rank, E);
    k_dinv<<<gN, 256, 0, stream>>>(counts, dinv, N);
    k_scan_block<<<nb, 256, 0, stream>>>(counts, bsums, N);
    k_scan_sums<<<1, 64, 0, stream>>>(bsums, nb);
    k_scan_final<<<nb, 256, 0, stream>>>(counts, bsums, rowptr, N);
    k_build<<<gE, 256, 0, stream>>>(ei, rank, rowptr, col, E);

    // layer 1
    k_gemm<256, false><<<gb, 256, 0, stream>>>(x, W1, dinv, A, N);
    k_aggr<<<gA, 256, 0, stream>>>(A, rowptr, col, dinv, b1, B, N);

    // layer 2 (relu fused on GEMM load)
    k_gemm<64, true><<<gb, 256, 0, stream>>>(B, W2, dinv, A, N);
    k_aggr<<<gA, 256, 0, stream>>>(A, rowptr, col, dinv, b2, B, N);

    // final FC
    k_fc<<<gA, 256, 0, stream>>>(B, Wfc, bfc, out, N);
}

// Round 5
// 529.196 us; speedup vs baseline: 2.0844x; 1.0903x over previous
//
#include <hip/hip_runtime.h>

#define NFEAT 64
#define SCAN_CHUNK 2048   // 256 threads x 8

// ---------------- async global->LDS helper (16B per lane, wave-uniform LDS base) ---
__device__ __forceinline__ void gll16(const float* g, float* l) {
    __builtin_amdgcn_global_load_lds(
        (const __attribute__((address_space(1))) unsigned int*)g,
        (__attribute__((address_space(3))) unsigned int*)l, 16, 0, 0);
}

// ---------------- degree / CSR build ----------------
__global__ void k_zero(int* p, int n) {
    int i = blockIdx.x * 256 + threadIdx.x;
    if (i < n) p[i] = 0;
}

// count in-degree AND capture each edge's rank within its dst bucket
__global__ void k_count(const int* __restrict__ ei, int* __restrict__ counts,
                        int* __restrict__ rank, int E) {
    int e = blockIdx.x * 256 + threadIdx.x;
    if (e < E) rank[e] = atomicAdd(&counts[ei[(size_t)E + e]], 1);
}

__global__ void k_dinv(const int* __restrict__ counts, float* dinv, int n) {
    int i = blockIdx.x * 256 + threadIdx.x;
    if (i < n) dinv[i] = rsqrtf((float)(counts[i] + 1));  // +1 self-loop
}

// phase A: per-block reduce of counts
__global__ __launch_bounds__(256) void k_scan_block(const int* __restrict__ counts,
                                                    int* __restrict__ bsums, int n) {
    __shared__ int red[256];
    int tid = threadIdx.x;
    int base = blockIdx.x * SCAN_CHUNK + tid * 8;
    int s = 0;
#pragma unroll
    for (int i = 0; i < 8; ++i) {
        int idx = base + i;
        s += (idx < n) ? counts[idx] : 0;
    }
    red[tid] = s;
    __syncthreads();
    for (int off = 128; off; off >>= 1) {
        if (tid < off) red[tid] += red[tid + off];
        __syncthreads();
    }
    if (tid == 0) bsums[blockIdx.x] = red[0];
}

// phase B: exclusive scan of block sums (nb <= 64), single block
__global__ void k_scan_sums(int* bsums, int nb) {
    __shared__ int ts[64];
    int tid = threadIdx.x;
    if (tid < 64) ts[tid] = (tid < nb) ? bsums[tid] : 0;
    __syncthreads();
    if (tid == 0) {
        int run = 0;
        for (int i = 0; i < nb; ++i) { int t = ts[i]; ts[i] = run; run += t; }
    }
    __syncthreads();
    if (tid < nb) bsums[tid] = ts[tid];
}

// phase C: full exclusive scan -> rowptr; rowptr[n]=E
__global__ __launch_bounds__(256) void k_scan_final(const int* __restrict__ counts,
                                                    const int* __restrict__ bsums,
                                                    int* __restrict__ rowptr, int n) {
    __shared__ int ts[256];
    int tid = threadIdx.x;
    int base0 = blockIdx.x * SCAN_CHUNK + tid * 8;
    int v[8], c[8];
    int s = 0;
#pragma unroll
    for (int i = 0; i < 8; ++i) {
        int idx = base0 + i;
        c[i] = (idx < n) ? counts[idx] : 0;
        v[i] = s;
        s += c[i];
    }
    ts[tid] = s;
    __syncthreads();
    for (int off = 1; off < 256; off <<= 1) {
        int t = (tid >= off) ? ts[tid - off] : 0;
        __syncthreads();
        if (tid >= off) ts[tid] += t;
        __syncthreads();
    }
    int texcl = ts[tid] - s;
    int base = bsums[blockIdx.x] + texcl;
#pragma unroll
    for (int i = 0; i < 8; ++i) {
        int idx = base0 + i;
        if (idx < n) {
            int val = base + v[i];
            rowptr[idx] = val;
            if (idx == n - 1) rowptr[n] = val + c[i];
        }
    }
}

// placement, atomic-free: col[rowptr[dst]+rank[e]] = src
__global__ void k_build(const int* __restrict__ ei, const int* __restrict__ rank,
                        const int* __restrict__ rowptr, int* __restrict__ col, int E) {
    int e = blockIdx.x * 256 + threadIdx.x;
    if (e >= E) return;
    int src = ei[e];
    int dst = ei[(size_t)E + e];
    col[rowptr[dst] + rank[e]] = src;
}

// ---------------- GEMM: H = dinv * (A @ W) ----------------
// Async global_load_lds staging (width=16), double-buffered LDS, 1 barrier/tile.
// LDS strides UNPADDED (32 / 64 floats) -- required for lane-contiguous deposit.
template<int K>
__global__ __launch_bounds__(256) void k_gemm(
    const float* __restrict__ A, const float* __restrict__ W,
    const float* __restrict__ dinv, float* __restrict__ H, int M)
{
    const int BM = 128, BK = 32;
    __shared__ float As[2 * BM * BK];   // [buf][m][k], stride 32
    __shared__ float Ws[2 * BK * NFEAT]; // [buf][k][n], stride 64

    int tid  = threadIdx.x;
    int w    = tid >> 6;
    int lane = tid & 63;
    int tx = tid & 15;
    int ty = tid >> 4;
    int m0 = blockIdx.x * BM;

    // per-lane source coords (chunk-relative): A: m_in_chunk=lane>>3, k=(lane&7)*4
    int a_ml = lane >> 3;
    int a_k  = (lane & 7) << 2;
    int w_kl = lane >> 4;
    int w_n  = (lane & 15) << 2;

    auto stage = [&](int k0, int buf) {
        // A tile: 16 chunks of 1 KB, wave w handles chunks w*4 .. w*4+3
#pragma unroll
        for (int rep = 0; rep < 4; ++rep) {
            int c = w * 4 + rep;
            int row = m0 + c * 8 + a_ml;
            if (row > M - 1) row = M - 1;       // clamp: garbage rows never stored
            gll16(A + (size_t)row * K + k0 + a_k,
                  &As[buf * (BM * BK) + c * 256]);
        }
        // W tile: 8 chunks, wave w handles chunks w*2, w*2+1
#pragma unroll
        for (int rep = 0; rep < 2; ++rep) {
            int c = w * 2 + rep;
            int kk = k0 + c * 4 + w_kl;
            gll16(W + (size_t)kk * NFEAT + w_n,
                  &Ws[buf * (BK * NFEAT) + c * 256]);
        }
    };

    float4 acc[8];
#pragma unroll
    for (int i = 0; i < 8; ++i) acc[i] = make_float4(0.f, 0.f, 0.f, 0.f);

    stage(0, 0);
    const int T = K / BK;
    for (int kt = 0; kt < T; ++kt) {
        __syncthreads();   // vmcnt drain: tile kt resident; prior compute done
        if (kt + 1 < T) stage((kt + 1) * BK, (kt + 1) & 1);
        const float* As_ = &As[(kt & 1) * (BM * BK)];
        const float* Ws_ = &Ws[(kt & 1) * (BK * NFEAT)];
#pragma unroll
        for (int kg = 0; kg < BK; kg += 4) {
            float4 w0 = *(const float4*)&Ws_[(kg + 0) * NFEAT + tx * 4];
            float4 w1 = *(const float4*)&Ws_[(kg + 1) * NFEAT + tx * 4];
            float4 w2 = *(const float4*)&Ws_[(kg + 2) * NFEAT + tx * 4];
            float4 w3 = *(const float4*)&Ws_[(kg + 3) * NFEAT + tx * 4];
#pragma unroll
            for (int i = 0; i < 8; ++i) {
                float4 a = *(const float4*)&As_[(i * 16 + ty) * BK + kg];
                acc[i].x = fmaf(a.x, w0.x, acc[i].x);
                acc[i].y = fmaf(a.x, w0.y, acc[i].y);
                acc[i].z = fmaf(a.x, w0.z, acc[i].z);
                acc[i].w = fmaf(a.x, w0.w, acc[i].w);
                acc[i].x = fmaf(a.y, w1.x, acc[i].x);
                acc[i].y = fmaf(a.y, w1.y, acc[i].y);
                acc[i].z = fmaf(a.y, w1.z, acc[i].z);
                acc[i].w = fmaf(a.y, w1.w, acc[i].w);
                acc[i].x = fmaf(a.z, w2.x, acc[i].x);
                acc[i].y = fmaf(a.z, w2.y, acc[i].y);
                acc[i].z = fmaf(a.z, w2.z, acc[i].z);
                acc[i].w = fmaf(a.z, w2.w, acc[i].w);
                acc[i].x = fmaf(a.w, w3.x, acc[i].x);
                acc[i].y = fmaf(a.w, w3.y, acc[i].y);
                acc[i].z = fmaf(a.w, w3.z, acc[i].z);
                acc[i].w = fmaf(a.w, w3.w, acc[i].w);
            }
        }
        __syncthreads();   // done reading buf before it is restaged
    }

    // epilogue: H = dinv[row] * acc (pre-scale so aggregation is unweighted)
#pragma unroll
    for (int i = 0; i < 8; ++i) {
        int row = m0 + i * 16 + ty;
        if (row < M) {
            float di = dinv[row];
            float4 h4 = make_float4(di * acc[i].x, di * acc[i].y,
                                    di * acc[i].z, di * acc[i].w);
            *(float4*)(H + (size_t)row * NFEAT + tx * 4) = h4;
        }
    }
}

// ---------------- CSR gather-aggregate (h pre-scaled by dinv) ------------------
// t = relu(bias + dinv[r]*(h[r] + sum_j h[col[j]]));  FC: out[r] = t @ Wfc + bfc
template<bool FC>
__global__ __launch_bounds__(256) void k_aggr(
    const float* __restrict__ h, const int* __restrict__ rowptr,
    const int* __restrict__ col, const float* __restrict__ dinv,
    const float* __restrict__ bias, const float* __restrict__ Wfc,
    const float* __restrict__ bfc, float* __restrict__ out, int n)
{
    __shared__ float Wl[NFEAT * 11 + 11];
    int tid = threadIdx.x;
    if (FC) {
        for (int i = tid; i < NFEAT * 11; i += 256) Wl[i] = Wfc[i];
        if (tid < 11) Wl[NFEAT * 11 + tid] = bfc[tid];
        __syncthreads();
    }
    int lane = tid & 63;
    int r = blockIdx.x * 4 + (tid >> 6);
    if (r >= n) return;                       // whole wave exits together
    int beg = rowptr[r], end = rowptr[r + 1];
    float acc = h[(size_t)r * NFEAT + lane];  // self-loop term
    int j = beg;
    for (; j + 3 < end; j += 4) {
        int c0 = col[j], c1 = col[j + 1], c2 = col[j + 2], c3 = col[j + 3];
        acc += h[(size_t)c0 * NFEAT + lane];
        acc += h[(size_t)c1 * NFEAT + lane];
        acc += h[(size_t)c2 * NFEAT + lane];
        acc += h[(size_t)c3 * NFEAT + lane];
    }
    for (; j < end; ++j) acc += h[(size_t)col[j] * NFEAT + lane];

    float t = fmaxf(bias[lane] + dinv[r] * acc, 0.f);   // relu fused here
    if (!FC) {
        out[(size_t)r * NFEAT + lane] = t;
    } else {
        float res = 0.f;
#pragma unroll
        for (int c = 0; c < 11; ++c) {
            float p = t * Wl[lane * 11 + c];
#pragma unroll
            for (int off = 32; off; off >>= 1) p += __shfl_xor(p, off, 64);
            if (lane == c) res = p + Wl[NFEAT * 11 + c];
        }
        if (lane < 11) out[(size_t)r * 11 + lane] = res;
    }
}

extern "C" void kernel_launch(void* const* d_in, const int* in_sizes, int n_in,
                              void* d_out, int out_size, void* d_ws, size_t ws_size,
                              hipStream_t stream) {
    const float* x   = (const float*)d_in[0];
    const int*   ei  = (const int*)d_in[1];
    const float* W1  = (const float*)d_in[2];
    const float* b1  = (const float*)d_in[3];
    const float* W2  = (const float*)d_in[4];
    const float* b2  = (const float*)d_in[5];
    const float* Wfc = (const float*)d_in[6];
    const float* bfc = (const float*)d_in[7];
    float* out = (float*)d_out;

    const int Fin = 256;
    int N = in_sizes[0] / Fin;      // 100000
    int E = in_sizes[1] / 2;        // 1600000

    char* ws = (char*)d_ws;
    size_t off = 0;
    auto alloc = [&](size_t bytes) { void* p = ws + off; off = (off + bytes + 255) & ~(size_t)255; return p; };
    int*   counts = (int*)  alloc((size_t)N * 4);
    int*   rowptr = (int*)  alloc((size_t)(N + 1) * 4);
    float* dinv   = (float*)alloc((size_t)N * 4);
    int*   bsums  = (int*)  alloc(64 * 4);
    int*   rank   = (int*)  alloc((size_t)E * 4);
    int*   col    = (int*)  alloc((size_t)E * 4);
    float* A      = (float*)alloc((size_t)N * NFEAT * 4);  // h buffer
    float* B      = (float*)alloc((size_t)N * NFEAT * 4);  // relu(out) buffer

    int gN = (N + 255) / 256;
    int gE = (E + 255) / 256;
    int gb = (N + 127) / 128;
    int gA = (N + 3) / 4;
    int nb = (N + SCAN_CHUNK - 1) / SCAN_CHUNK;   // 49 <= 64

    // CSR build (atomic-free placement via ranks)
    k_zero<<<gN, 256, 0, stream>>>(counts, N);
    k_count<<<gE, 256, 0, stream>>>(ei, counts, rank, E);
    k_dinv<<<gN, 256, 0, stream>>>(counts, dinv, N);
    k_scan_block<<<nb, 256, 0, stream>>>(counts, bsums, N);
    k_scan_sums<<<1, 64, 0, stream>>>(bsums, nb);
    k_scan_final<<<nb, 256, 0, stream>>>(counts, bsums, rowptr, N);
    k_build<<<gE, 256, 0, stream>>>(ei, rank, rowptr, col, E);

    // layer 1: h1=dinv*(x@W1); B = relu(b1 + dinv*(h1[r]+sum h1[col]))
    k_gemm<256><<<gb, 256, 0, stream>>>(x, W1, dinv, A, N);
    k_aggr<false><<<gA, 256, 0, stream>>>(A, rowptr, col, dinv, b1, nullptr, nullptr, B, N);

    // layer 2: h2=dinv*(B@W2); fused aggr+relu+FC -> out
    k_gemm<64><<<gb, 256, 0, stream>>>(B, W2, dinv, A, N);
    k_aggr<true><<<gA, 256, 0, stream>>>(A, rowptr, col, dinv, b2, Wfc, bfc, out, N);
}

// Round 6
// 481.261 us; speedup vs baseline: 2.2920x; 1.0996x over previous
//
#include <hip/hip_runtime.h>
#include <hip/hip_fp16.h>

#define NFEAT 64
#define SCAN_CHUNK 2048   // 256 threads x 8

// ---------------- async global->LDS helper (16B per lane, wave-uniform LDS base) ---
__device__ __forceinline__ void gll16(const float* g, float* l) {
    __builtin_amdgcn_global_load_lds(
        (const __attribute__((address_space(1))) unsigned int*)g,
        (__attribute__((address_space(3))) unsigned int*)l, 16, 0, 0);
}

// ---------------- degree / CSR build ----------------
__global__ void k_zero(int* p, int n) {
    int i = blockIdx.x * 256 + threadIdx.x;
    if (i < n) p[i] = 0;
}

// count in-degree AND capture each edge's rank within its dst bucket
__global__ void k_count(const int* __restrict__ ei, int* __restrict__ counts,
                        int* __restrict__ rank, int E) {
    int e = blockIdx.x * 256 + threadIdx.x;
    if (e < E) rank[e] = atomicAdd(&counts[ei[(size_t)E + e]], 1);
}

__global__ void k_dinv(const int* __restrict__ counts, float* dinv, int n) {
    int i = blockIdx.x * 256 + threadIdx.x;
    if (i < n) dinv[i] = rsqrtf((float)(counts[i] + 1));  // +1 self-loop
}

// phase A: per-block reduce of counts
__global__ __launch_bounds__(256) void k_scan_block(const int* __restrict__ counts,
                                                    int* __restrict__ bsums, int n) {
    __shared__ int red[256];
    int tid = threadIdx.x;
    int base = blockIdx.x * SCAN_CHUNK + tid * 8;
    int s = 0;
#pragma unroll
    for (int i = 0; i < 8; ++i) {
        int idx = base + i;
        s += (idx < n) ? counts[idx] : 0;
    }
    red[tid] = s;
    __syncthreads();
    for (int off = 128; off; off >>= 1) {
        if (tid < off) red[tid] += red[tid + off];
        __syncthreads();
    }
    if (tid == 0) bsums[blockIdx.x] = red[0];
}

// phase B: exclusive scan of block sums (nb <= 64), single block
__global__ void k_scan_sums(int* bsums, int nb) {
    __shared__ int ts[64];
    int tid = threadIdx.x;
    if (tid < 64) ts[tid] = (tid < nb) ? bsums[tid] : 0;
    __syncthreads();
    if (tid == 0) {
        int run = 0;
        for (int i = 0; i < nb; ++i) { int t = ts[i]; ts[i] = run; run += t; }
    }
    __syncthreads();
    if (tid < nb) bsums[tid] = ts[tid];
}

// phase C: full exclusive scan -> rowptr; rowptr[n]=E
__global__ __launch_bounds__(256) void k_scan_final(const int* __restrict__ counts,
                                                    const int* __restrict__ bsums,
                                                    int* __restrict__ rowptr, int n) {
    __shared__ int ts[256];
    int tid = threadIdx.x;
    int base0 = blockIdx.x * SCAN_CHUNK + tid * 8;
    int v[8], c[8];
    int s = 0;
#pragma unroll
    for (int i = 0; i < 8; ++i) {
        int idx = base0 + i;
        c[i] = (idx < n) ? counts[idx] : 0;
        v[i] = s;
        s += c[i];
    }
    ts[tid] = s;
    __syncthreads();
    for (int off = 1; off < 256; off <<= 1) {
        int t = (tid >= off) ? ts[tid - off] : 0;
        __syncthreads();
        if (tid >= off) ts[tid] += t;
        __syncthreads();
    }
    int texcl = ts[tid] - s;
    int base = bsums[blockIdx.x] + texcl;
#pragma unroll
    for (int i = 0; i < 8; ++i) {
        int idx = base0 + i;
        if (idx < n) {
            int val = base + v[i];
            rowptr[idx] = val;
            if (idx == n - 1) rowptr[n] = val + c[i];
        }
    }
}

// placement, atomic-free: col[rowptr[dst]+rank[e]] = src
__global__ void k_build(const int* __restrict__ ei, const int* __restrict__ rank,
                        const int* __restrict__ rowptr, int* __restrict__ col, int E) {
    int e = blockIdx.x * 256 + threadIdx.x;
    if (e >= E) return;
    int src = ei[e];
    int dst = ei[(size_t)E + e];
    col[rowptr[dst] + rank[e]] = src;
}

// ---------------- GEMM: H(fp16) = dinv * (A @ W) ----------------
// Async global_load_lds staging (width=16), double-buffered LDS, 1 barrier/tile.
// LDS strides UNPADDED (32 / 64 floats) -- required for lane-contiguous deposit.
template<int K>
__global__ __launch_bounds__(256) void k_gemm(
    const float* __restrict__ A, const float* __restrict__ W,
    const float* __restrict__ dinv, __half* __restrict__ H, int M)
{
    const int BM = 128, BK = 32;
    __shared__ float As[2 * BM * BK];    // [buf][m][k], stride 32
    __shared__ float Ws[2 * BK * NFEAT]; // [buf][k][n], stride 64

    int tid  = threadIdx.x;
    int w    = tid >> 6;
    int lane = tid & 63;
    int tx = tid & 15;
    int ty = tid >> 4;
    int m0 = blockIdx.x * BM;

    int a_ml = lane >> 3;
    int a_k  = (lane & 7) << 2;
    int w_kl = lane >> 4;
    int w_n  = (lane & 15) << 2;

    auto stage = [&](int k0, int buf) {
#pragma unroll
        for (int rep = 0; rep < 4; ++rep) {
            int c = w * 4 + rep;
            int row = m0 + c * 8 + a_ml;
            if (row > M - 1) row = M - 1;       // clamp: garbage rows never stored
            gll16(A + (size_t)row * K + k0 + a_k,
                  &As[buf * (BM * BK) + c * 256]);
        }
#pragma unroll
        for (int rep = 0; rep < 2; ++rep) {
            int c = w * 2 + rep;
            int kk = k0 + c * 4 + w_kl;
            gll16(W + (size_t)kk * NFEAT + w_n,
                  &Ws[buf * (BK * NFEAT) + c * 256]);
        }
    };

    float4 acc[8];
#pragma unroll
    for (int i = 0; i < 8; ++i) acc[i] = make_float4(0.f, 0.f, 0.f, 0.f);

    stage(0, 0);
    const int T = K / BK;
    for (int kt = 0; kt < T; ++kt) {
        __syncthreads();
        if (kt + 1 < T) stage((kt + 1) * BK, (kt + 1) & 1);
        const float* As_ = &As[(kt & 1) * (BM * BK)];
        const float* Ws_ = &Ws[(kt & 1) * (BK * NFEAT)];
#pragma unroll
        for (int kg = 0; kg < BK; kg += 4) {
            float4 w0 = *(const float4*)&Ws_[(kg + 0) * NFEAT + tx * 4];
            float4 w1 = *(const float4*)&Ws_[(kg + 1) * NFEAT + tx * 4];
            float4 w2 = *(const float4*)&Ws_[(kg + 2) * NFEAT + tx * 4];
            float4 w3 = *(const float4*)&Ws_[(kg + 3) * NFEAT + tx * 4];
#pragma unroll
            for (int i = 0; i < 8; ++i) {
                float4 a = *(const float4*)&As_[(i * 16 + ty) * BK + kg];
                acc[i].x = fmaf(a.x, w0.x, acc[i].x);
                acc[i].y = fmaf(a.x, w0.y, acc[i].y);
                acc[i].z = fmaf(a.x, w0.z, acc[i].z);
                acc[i].w = fmaf(a.x, w0.w, acc[i].w);
                acc[i].x = fmaf(a.y, w1.x, acc[i].x);
                acc[i].y = fmaf(a.y, w1.y, acc[i].y);
                acc[i].z = fmaf(a.y, w1.z, acc[i].z);
                acc[i].w = fmaf(a.y, w1.w, acc[i].w);
                acc[i].x = fmaf(a.z, w2.x, acc[i].x);
                acc[i].y = fmaf(a.z, w2.y, acc[i].y);
                acc[i].z = fmaf(a.z, w2.z, acc[i].z);
                acc[i].w = fmaf(a.z, w2.w, acc[i].w);
                acc[i].x = fmaf(a.w, w3.x, acc[i].x);
                acc[i].y = fmaf(a.w, w3.y, acc[i].y);
                acc[i].z = fmaf(a.w, w3.z, acc[i].z);
                acc[i].w = fmaf(a.w, w3.w, acc[i].w);
            }
        }
        __syncthreads();
    }

    // epilogue: H = fp16(dinv[row] * acc)  (pre-scaled; halves gather bytes)
#pragma unroll
    for (int i = 0; i < 8; ++i) {
        int row = m0 + i * 16 + ty;
        if (row < M) {
            float di = dinv[row];
            __half2 lo = __float22half2_rn(make_float2(di * acc[i].x, di * acc[i].y));
            __half2 hi = __float22half2_rn(make_float2(di * acc[i].z, di * acc[i].w));
            uint2 u;
            u.x = __builtin_bit_cast(unsigned int, lo);
            u.y = __builtin_bit_cast(unsigned int, hi);
            *(uint2*)(H + (size_t)row * NFEAT + tx * 4) = u;  // 8B aligned
        }
    }
}

// ---------------- CSR gather-aggregate (h fp16, pre-scaled by dinv) -------------
// 4 edge-slots per wave (16 lanes x uint2 = 128B row), unroll x2 = 8 gathers in flight.
// t = relu(bias + dinv[r]*(h[r] + sum_j h[col[j]]));  FC: out[r] = t @ Wfc + bfc
template<bool FC>
__global__ __launch_bounds__(256) void k_aggr(
    const __half* __restrict__ h, const int* __restrict__ rowptr,
    const int* __restrict__ col, const float* __restrict__ dinv,
    const float* __restrict__ bias, const float* __restrict__ Wfc,
    const float* __restrict__ bfc, float* __restrict__ out, int n)
{
    __shared__ float Wl[NFEAT * 11 + 11];
    int tid = threadIdx.x;
    if (FC) {
        for (int i = tid; i < NFEAT * 11; i += 256) Wl[i] = Wfc[i];
        if (tid < 11) Wl[NFEAT * 11 + tid] = bfc[tid];
        __syncthreads();
    }
    int lane = tid & 63;
    int g = lane >> 4;            // edge slot 0..3
    int fi = (lane & 15) << 2;    // feature quad base
    int r = blockIdx.x * 4 + (tid >> 6);
    if (r >= n) return;           // whole wave exits together

    int beg = rowptr[r], end = rowptr[r + 1];
    float4 acc = make_float4(0.f, 0.f, 0.f, 0.f);

    auto fetch_add = [&](int src) {
        uint2 u = *(const uint2*)(h + (size_t)src * NFEAT + fi);
        float2 lo = __half22float2(__builtin_bit_cast(__half2, u.x));
        float2 hi = __half22float2(__builtin_bit_cast(__half2, u.y));
        acc.x += lo.x; acc.y += lo.y; acc.z += hi.x; acc.w += hi.y;
    };

    if (g == 0) fetch_add(r);     // self-loop (slot 0 only)
    int j = beg + g;
    for (; j + 4 < end; j += 8) {       // both slots valid: 8 gathers in flight/wave
        int s0 = col[j];
        int s1 = col[j + 4];
        uint2 u0 = *(const uint2*)(h + (size_t)s0 * NFEAT + fi);
        uint2 u1 = *(const uint2*)(h + (size_t)s1 * NFEAT + fi);
        float2 a0 = __half22float2(__builtin_bit_cast(__half2, u0.x));
        float2 b0 = __half22float2(__builtin_bit_cast(__half2, u0.y));
        float2 a1 = __half22float2(__builtin_bit_cast(__half2, u1.x));
        float2 b1 = __half22float2(__builtin_bit_cast(__half2, u1.y));
        acc.x += a0.x + a1.x; acc.y += a0.y + a1.y;
        acc.z += b0.x + b1.x; acc.w += b0.y + b1.y;
    }
    for (; j < end; j += 4) fetch_add(col[j]);

    // combine the 4 slots: after xor16+xor32 every lane holds the full sum
    acc.x += __shfl_xor(acc.x, 16, 64); acc.y += __shfl_xor(acc.y, 16, 64);
    acc.z += __shfl_xor(acc.z, 16, 64); acc.w += __shfl_xor(acc.w, 16, 64);
    acc.x += __shfl_xor(acc.x, 32, 64); acc.y += __shfl_xor(acc.y, 32, 64);
    acc.z += __shfl_xor(acc.z, 32, 64); acc.w += __shfl_xor(acc.w, 32, 64);

    float di = dinv[r];
    float4 bb = *(const float4*)(bias + fi);
    float4 t;
    t.x = fmaxf(bb.x + di * acc.x, 0.f);
    t.y = fmaxf(bb.y + di * acc.y, 0.f);
    t.z = fmaxf(bb.z + di * acc.z, 0.f);
    t.w = fmaxf(bb.w + di * acc.w, 0.f);

    if (!FC) {
        if (g == 0) *(float4*)(out + (size_t)r * NFEAT + fi) = t;  // 16 lanes x 16B
    } else {
#pragma unroll
        for (int c = 0; c < 11; ++c) {
            float p = t.x * Wl[(fi + 0) * 11 + c] + t.y * Wl[(fi + 1) * 11 + c]
                    + t.z * Wl[(fi + 2) * 11 + c] + t.w * Wl[(fi + 3) * 11 + c];
            p += __shfl_xor(p, 8, 64);
            p += __shfl_xor(p, 4, 64);
            p += __shfl_xor(p, 2, 64);
            p += __shfl_xor(p, 1, 64);
            if (lane == c) out[(size_t)r * 11 + lane] = p + Wl[NFEAT * 11 + c];
        }
    }
}

extern "C" void kernel_launch(void* const* d_in, const int* in_sizes, int n_in,
                              void* d_out, int out_size, void* d_ws, size_t ws_size,
                              hipStream_t stream) {
    const float* x   = (const float*)d_in[0];
    const int*   ei  = (const int*)d_in[1];
    const float* W1  = (const float*)d_in[2];
    const float* b1  = (const float*)d_in[3];
    const float* W2  = (const float*)d_in[4];
    const float* b2  = (const float*)d_in[5];
    const float* Wfc = (const float*)d_in[6];
    const float* bfc = (const float*)d_in[7];
    float* out = (float*)d_out;

    const int Fin = 256;
    int N = in_sizes[0] / Fin;      // 100000
    int E = in_sizes[1] / 2;        // 1600000

    char* ws = (char*)d_ws;
    size_t off = 0;
    auto alloc = [&](size_t bytes) { void* p = ws + off; off = (off + bytes + 255) & ~(size_t)255; return p; };
    int*    counts = (int*)   alloc((size_t)N * 4);
    int*    rowptr = (int*)   alloc((size_t)(N + 1) * 4);
    float*  dinv   = (float*) alloc((size_t)N * 4);
    int*    bsums  = (int*)   alloc(64 * 4);
    int*    rank   = (int*)   alloc((size_t)E * 4);
    int*    col    = (int*)   alloc((size_t)E * 4);
    __half* A      = (__half*)alloc((size_t)N * NFEAT * 2);  // h buffer (fp16)
    float*  B      = (float*) alloc((size_t)N * NFEAT * 4);  // relu(out1) buffer

    int gN = (N + 255) / 256;
    int gE = (E + 255) / 256;
    int gb = (N + 127) / 128;
    int gA = (N + 3) / 4;
    int nb = (N + SCAN_CHUNK - 1) / SCAN_CHUNK;   // 49 <= 64

    // CSR build (atomic-free placement via ranks)
    k_zero<<<gN, 256, 0, stream>>>(counts, N);
    k_count<<<gE, 256, 0, stream>>>(ei, counts, rank, E);
    k_dinv<<<gN, 256, 0, stream>>>(counts, dinv, N);
    k_scan_block<<<nb, 256, 0, stream>>>(counts, bsums, N);
    k_scan_sums<<<1, 64, 0, stream>>>(bsums, nb);
    k_scan_final<<<nb, 256, 0, stream>>>(counts, bsums, rowptr, N);
    k_build<<<gE, 256, 0, stream>>>(ei, rank, rowptr, col, E);

    // layer 1: h1=fp16(dinv*(x@W1)); B = relu(b1 + dinv*(h1[r]+sum h1[col]))
    k_gemm<256><<<gb, 256, 0, stream>>>(x, W1, dinv, A, N);
    k_aggr<false><<<gA, 256, 0, stream>>>(A, rowptr, col, dinv, b1, nullptr, nullptr, B, N);

    // layer 2: h2=fp16(dinv*(B@W2)); fused aggr+relu+FC -> out
    k_gemm<64><<<gb, 256, 0, stream>>>(B, W2, dinv, A, N);
    k_aggr<true><<<gA, 256, 0, stream>>>(A, rowptr, col, dinv, b2, Wfc, bfc, out, N);
}

// Round 7
// 477.105 us; speedup vs baseline: 2.3120x; 1.0087x over previous
//
#include <hip/hip_runtime.h>
#include <hip/hip_fp16.h>

#define NFEAT 64
#define SCAN_CHUNK 2048   // 256 threads x 8

// ---------------- async global->LDS helper (16B per lane, wave-uniform LDS base) ---
__device__ __forceinline__ void gll16(const float* g, float* l) {
    __builtin_amdgcn_global_load_lds(
        (const __attribute__((address_space(1))) unsigned int*)g,
        (__attribute__((address_space(3))) unsigned int*)l, 16, 0, 0);
}

__device__ __forceinline__ __half2 bch(unsigned int u) {
    return __builtin_bit_cast(__half2, u);
}

// ---------------- degree / CSR build ----------------
__global__ void k_zero(int* p, int n) {
    int i = blockIdx.x * 256 + threadIdx.x;
    if (i < n) p[i] = 0;
}

// count in-degree AND capture each edge's rank within its dst bucket
__global__ void k_count(const int* __restrict__ ei, int* __restrict__ counts,
                        int* __restrict__ rank, int E) {
    int e = blockIdx.x * 256 + threadIdx.x;
    if (e < E) rank[e] = atomicAdd(&counts[ei[(size_t)E + e]], 1);
}

__global__ void k_dinv(const int* __restrict__ counts, float* dinv, int n) {
    int i = blockIdx.x * 256 + threadIdx.x;
    if (i < n) dinv[i] = rsqrtf((float)(counts[i] + 1));  // +1 self-loop
}

// phase A: per-block reduce of counts
__global__ __launch_bounds__(256) void k_scan_block(const int* __restrict__ counts,
                                                    int* __restrict__ bsums, int n) {
    __shared__ int red[256];
    int tid = threadIdx.x;
    int base = blockIdx.x * SCAN_CHUNK + tid * 8;
    int s = 0;
#pragma unroll
    for (int i = 0; i < 8; ++i) {
        int idx = base + i;
        s += (idx < n) ? counts[idx] : 0;
    }
    red[tid] = s;
    __syncthreads();
    for (int off = 128; off; off >>= 1) {
        if (tid < off) red[tid] += red[tid + off];
        __syncthreads();
    }
    if (tid == 0) bsums[blockIdx.x] = red[0];
}

// phase B: exclusive scan of block sums (nb <= 64), single block
__global__ void k_scan_sums(int* bsums, int nb) {
    __shared__ int ts[64];
    int tid = threadIdx.x;
    if (tid < 64) ts[tid] = (tid < nb) ? bsums[tid] : 0;
    __syncthreads();
    if (tid == 0) {
        int run = 0;
        for (int i = 0; i < nb; ++i) { int t = ts[i]; ts[i] = run; run += t; }
    }
    __syncthreads();
    if (tid < nb) bsums[tid] = ts[tid];
}

// phase C: full exclusive scan -> rowptr; rowptr[n]=E
__global__ __launch_bounds__(256) void k_scan_final(const int* __restrict__ counts,
                                                    const int* __restrict__ bsums,
                                                    int* __restrict__ rowptr, int n) {
    __shared__ int ts[256];
    int tid = threadIdx.x;
    int base0 = blockIdx.x * SCAN_CHUNK + tid * 8;
    int v[8], c[8];
    int s = 0;
#pragma unroll
    for (int i = 0; i < 8; ++i) {
        int idx = base0 + i;
        c[i] = (idx < n) ? counts[idx] : 0;
        v[i] = s;
        s += c[i];
    }
    ts[tid] = s;
    __syncthreads();
    for (int off = 1; off < 256; off <<= 1) {
        int t = (tid >= off) ? ts[tid - off] : 0;
        __syncthreads();
        if (tid >= off) ts[tid] += t;
        __syncthreads();
    }
    int texcl = ts[tid] - s;
    int base = bsums[blockIdx.x] + texcl;
#pragma unroll
    for (int i = 0; i < 8; ++i) {
        int idx = base0 + i;
        if (idx < n) {
            int val = base + v[i];
            rowptr[idx] = val;
            if (idx == n - 1) rowptr[n] = val + c[i];
        }
    }
}

// placement, atomic-free: col[rowptr[dst]+rank[e]] = src
__global__ void k_build(const int* __restrict__ ei, const int* __restrict__ rank,
                        const int* __restrict__ rowptr, int* __restrict__ col, int E) {
    int e = blockIdx.x * 256 + threadIdx.x;
    if (e >= E) return;
    int src = ei[e];
    int dst = ei[(size_t)E + e];
    col[rowptr[dst] + rank[e]] = src;
}

// ---------------- GEMM: H(fp16) = dinv * (A @ W) ----------------
// Async global_load_lds staging (width=16), double-buffered LDS, 1 barrier/tile.
// LDS strides UNPADDED (32 / 64 floats) -- required for lane-contiguous deposit.
template<int K>
__global__ __launch_bounds__(256) void k_gemm(
    const float* __restrict__ A, const float* __restrict__ W,
    const float* __restrict__ dinv, __half* __restrict__ H, int M)
{
    const int BM = 128, BK = 32;
    __shared__ float As[2 * BM * BK];    // [buf][m][k], stride 32
    __shared__ float Ws[2 * BK * NFEAT]; // [buf][k][n], stride 64

    int tid  = threadIdx.x;
    int w    = tid >> 6;
    int lane = tid & 63;
    int tx = tid & 15;
    int ty = tid >> 4;
    int m0 = blockIdx.x * BM;

    int a_ml = lane >> 3;
    int a_k  = (lane & 7) << 2;
    int w_kl = lane >> 4;
    int w_n  = (lane & 15) << 2;

    auto stage = [&](int k0, int buf) {
#pragma unroll
        for (int rep = 0; rep < 4; ++rep) {
            int c = w * 4 + rep;
            int row = m0 + c * 8 + a_ml;
            if (row > M - 1) row = M - 1;       // clamp: garbage rows never stored
            gll16(A + (size_t)row * K + k0 + a_k,
                  &As[buf * (BM * BK) + c * 256]);
        }
#pragma unroll
        for (int rep = 0; rep < 2; ++rep) {
            int c = w * 2 + rep;
            int kk = k0 + c * 4 + w_kl;
            gll16(W + (size_t)kk * NFEAT + w_n,
                  &Ws[buf * (BK * NFEAT) + c * 256]);
        }
    };

    float4 acc[8];
#pragma unroll
    for (int i = 0; i < 8; ++i) acc[i] = make_float4(0.f, 0.f, 0.f, 0.f);

    stage(0, 0);
    const int T = K / BK;
    for (int kt = 0; kt < T; ++kt) {
        __syncthreads();
        if (kt + 1 < T) stage((kt + 1) * BK, (kt + 1) & 1);
        const float* As_ = &As[(kt & 1) * (BM * BK)];
        const float* Ws_ = &Ws[(kt & 1) * (BK * NFEAT)];
#pragma unroll
        for (int kg = 0; kg < BK; kg += 4) {
            float4 w0 = *(const float4*)&Ws_[(kg + 0) * NFEAT + tx * 4];
            float4 w1 = *(const float4*)&Ws_[(kg + 1) * NFEAT + tx * 4];
            float4 w2 = *(const float4*)&Ws_[(kg + 2) * NFEAT + tx * 4];
            float4 w3 = *(const float4*)&Ws_[(kg + 3) * NFEAT + tx * 4];
#pragma unroll
            for (int i = 0; i < 8; ++i) {
                float4 a = *(const float4*)&As_[(i * 16 + ty) * BK + kg];
                acc[i].x = fmaf(a.x, w0.x, acc[i].x);
                acc[i].y = fmaf(a.x, w0.y, acc[i].y);
                acc[i].z = fmaf(a.x, w0.z, acc[i].z);
                acc[i].w = fmaf(a.x, w0.w, acc[i].w);
                acc[i].x = fmaf(a.y, w1.x, acc[i].x);
                acc[i].y = fmaf(a.y, w1.y, acc[i].y);
                acc[i].z = fmaf(a.y, w1.z, acc[i].z);
                acc[i].w = fmaf(a.y, w1.w, acc[i].w);
                acc[i].x = fmaf(a.z, w2.x, acc[i].x);
                acc[i].y = fmaf(a.z, w2.y, acc[i].y);
                acc[i].z = fmaf(a.z, w2.z, acc[i].z);
                acc[i].w = fmaf(a.z, w2.w, acc[i].w);
                acc[i].x = fmaf(a.w, w3.x, acc[i].x);
                acc[i].y = fmaf(a.w, w3.y, acc[i].y);
                acc[i].z = fmaf(a.w, w3.z, acc[i].z);
                acc[i].w = fmaf(a.w, w3.w, acc[i].w);
            }
        }
        __syncthreads();
    }

    // epilogue: H = fp16(dinv[row] * acc)  (pre-scaled; halves gather bytes)
#pragma unroll
    for (int i = 0; i < 8; ++i) {
        int row = m0 + i * 16 + ty;
        if (row < M) {
            float di = dinv[row];
            __half2 lo = __float22half2_rn(make_float2(di * acc[i].x, di * acc[i].y));
            __half2 hi = __float22half2_rn(make_float2(di * acc[i].z, di * acc[i].w));
            uint2 u;
            u.x = __builtin_bit_cast(unsigned int, lo);
            u.y = __builtin_bit_cast(unsigned int, hi);
            *(uint2*)(H + (size_t)row * NFEAT + tx * 4) = u;  // 8B aligned
        }
    }
}

// ---------------- CSR gather-aggregate (h fp16, pre-scaled by dinv) -------------
// 4 edge-slots/wave; unroll x4 per slot = 16 gathers in flight; pairwise pk-fp16 fold.
// t = relu(bias + dinv[r]*(h[r] + sum_j h[col[j]]));  FC: out[r] = t @ Wfc + bfc
template<bool FC>
__global__ __launch_bounds__(256) void k_aggr(
    const __half* __restrict__ h, const int* __restrict__ rowptr,
    const int* __restrict__ col, const float* __restrict__ dinv,
    const float* __restrict__ bias, const float* __restrict__ Wfc,
    const float* __restrict__ bfc, float* __restrict__ out, int n)
{
    __shared__ float Wl[NFEAT * 11 + 11];
    int tid = threadIdx.x;
    if (FC) {
        for (int i = tid; i < NFEAT * 11; i += 256) Wl[i] = Wfc[i];
        if (tid < 11) Wl[NFEAT * 11 + tid] = bfc[tid];
        __syncthreads();
    }
    int lane = tid & 63;
    int g = lane >> 4;            // edge slot 0..3
    int fi = (lane & 15) << 2;    // feature quad base
    int r = blockIdx.x * 4 + (tid >> 6);
    if (r >= n) return;           // whole wave exits together

    int beg = rowptr[r], end = rowptr[r + 1];
    const __half* hp = h + fi;
    float4 acc = make_float4(0.f, 0.f, 0.f, 0.f);

    auto ld = [&](int src) { return *(const uint2*)(hp + (size_t)src * NFEAT); };
    auto addu = [&](uint2 u) {
        float2 lo = __half22float2(bch(u.x));
        float2 hi = __half22float2(bch(u.y));
        acc.x += lo.x; acc.y += lo.y; acc.z += hi.x; acc.w += hi.y;
    };

    if (g == 0) addu(ld(r));      // self-loop (slot 0, fp32 path)
    int j = beg + g;
    // main: 4 gathers in flight per slot (16/wave); pairwise fp16 fold
    for (; j + 12 < end; j += 16) {
        int s0 = col[j], s1 = col[j + 4], s2 = col[j + 8], s3 = col[j + 12];
        uint2 u0 = ld(s0), u1 = ld(s1), u2 = ld(s2), u3 = ld(s3);
        __half2 p0 = __hadd2(bch(u0.x), bch(u1.x));
        __half2 p1 = __hadd2(bch(u0.y), bch(u1.y));
        __half2 q0 = __hadd2(bch(u2.x), bch(u3.x));
        __half2 q1 = __hadd2(bch(u2.y), bch(u3.y));
        float2 a0 = __half22float2(p0), a1 = __half22float2(p1);
        float2 c0 = __half22float2(q0), c1 = __half22float2(q1);
        acc.x += a0.x + c0.x; acc.y += a0.y + c0.y;
        acc.z += a1.x + c1.x; acc.w += a1.y + c1.y;
    }
    for (; j + 4 < end; j += 8) {      // 2 in flight, fp32 fold
        uint2 u0 = ld(col[j]), u1 = ld(col[j + 4]);
        float2 a0 = __half22float2(bch(u0.x)), b0 = __half22float2(bch(u0.y));
        float2 a1 = __half22float2(bch(u1.x)), b1 = __half22float2(bch(u1.y));
        acc.x += a0.x + a1.x; acc.y += a0.y + a1.y;
        acc.z += b0.x + b1.x; acc.w += b0.y + b1.y;
    }
    for (; j < end; j += 4) addu(ld(col[j]));

    // combine the 4 slots: after xor16+xor32 every lane holds the full sum
    acc.x += __shfl_xor(acc.x, 16, 64); acc.y += __shfl_xor(acc.y, 16, 64);
    acc.z += __shfl_xor(acc.z, 16, 64); acc.w += __shfl_xor(acc.w, 16, 64);
    acc.x += __shfl_xor(acc.x, 32, 64); acc.y += __shfl_xor(acc.y, 32, 64);
    acc.z += __shfl_xor(acc.z, 32, 64); acc.w += __shfl_xor(acc.w, 32, 64);

    float di = dinv[r];
    float4 bb = *(const float4*)(bias + fi);
    float4 t;
    t.x = fmaxf(bb.x + di * acc.x, 0.f);
    t.y = fmaxf(bb.y + di * acc.y, 0.f);
    t.z = fmaxf(bb.z + di * acc.z, 0.f);
    t.w = fmaxf(bb.w + di * acc.w, 0.f);

    if (!FC) {
        if (g == 0) *(float4*)(out + (size_t)r * NFEAT + fi) = t;  // 16 lanes x 16B
    } else {
#pragma unroll
        for (int c = 0; c < 11; ++c) {
            float p = t.x * Wl[(fi + 0) * 11 + c] + t.y * Wl[(fi + 1) * 11 + c]
                    + t.z * Wl[(fi + 2) * 11 + c] + t.w * Wl[(fi + 3) * 11 + c];
            p += __shfl_xor(p, 8, 64);
            p += __shfl_xor(p, 4, 64);
            p += __shfl_xor(p, 2, 64);
            p += __shfl_xor(p, 1, 64);
            if (lane == c) out[(size_t)r * 11 + lane] = p + Wl[NFEAT * 11 + c];
        }
    }
}

extern "C" void kernel_launch(void* const* d_in, const int* in_sizes, int n_in,
                              void* d_out, int out_size, void* d_ws, size_t ws_size,
                              hipStream_t stream) {
    const float* x   = (const float*)d_in[0];
    const int*   ei  = (const int*)d_in[1];
    const float* W1  = (const float*)d_in[2];
    const float* b1  = (const float*)d_in[3];
    const float* W2  = (const float*)d_in[4];
    const float* b2  = (const float*)d_in[5];
    const float* Wfc = (const float*)d_in[6];
    const float* bfc = (const float*)d_in[7];
    float* out = (float*)d_out;

    const int Fin = 256;
    int N = in_sizes[0] / Fin;      // 100000
    int E = in_sizes[1] / 2;        // 1600000

    char* ws = (char*)d_ws;
    size_t off = 0;
    auto alloc = [&](size_t bytes) { void* p = ws + off; off = (off + bytes + 255) & ~(size_t)255; return p; };
    int*    counts = (int*)   alloc((size_t)N * 4);
    int*    rowptr = (int*)   alloc((size_t)(N + 1) * 4);
    float*  dinv   = (float*) alloc((size_t)N * 4);
    int*    bsums  = (int*)   alloc(64 * 4);
    int*    rank   = (int*)   alloc((size_t)E * 4);
    int*    col    = (int*)   alloc((size_t)E * 4);
    __half* A      = (__half*)alloc((size_t)N * NFEAT * 2);  // h buffer (fp16)
    float*  B      = (float*) alloc((size_t)N * NFEAT * 4);  // relu(out1) buffer

    int gN = (N + 255) / 256;
    int gE = (E + 255) / 256;
    int gb = (N + 127) / 128;
    int gA = (N + 3) / 4;
    int nb = (N + SCAN_CHUNK - 1) / SCAN_CHUNK;   // 49 <= 64

    // CSR build (atomic-free placement via ranks)
    k_zero<<<gN, 256, 0, stream>>>(counts, N);
    k_count<<<gE, 256, 0, stream>>>(ei, counts, rank, E);
    k_dinv<<<gN, 256, 0, stream>>>(counts, dinv, N);
    k_scan_block<<<nb, 256, 0, stream>>>(counts, bsums, N);
    k_scan_sums<<<1, 64, 0, stream>>>(bsums, nb);
    k_scan_final<<<nb, 256, 0, stream>>>(counts, bsums, rowptr, N);
    k_build<<<gE, 256, 0, stream>>>(ei, rank, rowptr, col, E);

    // layer 1: h1=fp16(dinv*(x@W1)); B = relu(b1 + dinv*(h1[r]+sum h1[col]))
    k_gemm<256><<<gb, 256, 0, stream>>>(x, W1, dinv, A, N);
    k_aggr<false><<<gA, 256, 0, stream>>>(A, rowptr, col, dinv, b1, nullptr, nullptr, B, N);

    // layer 2: h2=fp16(dinv*(B@W2)); fused aggr+relu+FC -> out
    k_gemm<64><<<gb, 256, 0, stream>>>(B, W2, dinv, A, N);
    k_aggr<true><<<gA, 256, 0, stream>>>(A, rowptr, col, dinv, b2, Wfc, bfc, out, N);
}

// Round 8
// 412.465 us; speedup vs baseline: 2.6743x; 1.1567x over previous
//
#include <hip/hip_runtime.h>
#include <hip/hip_fp16.h>

#define NFEAT 64
#define SCAN_CHUNK 2048   // 256 threads x 8

// ---------------- async global->LDS helper (16B per lane, wave-uniform LDS base) ---
__device__ __forceinline__ void gll16(const float* g, float* l) {
    __builtin_amdgcn_global_load_lds(
        (const __attribute__((address_space(1))) unsigned int*)g,
        (__attribute__((address_space(3))) unsigned int*)l, 16, 0, 0);
}

__device__ __forceinline__ __half2 bch(unsigned int u) {
    return __builtin_bit_cast(__half2, u);
}

// ---------------- degree / CSR build ----------------
__global__ void k_zero(int* p, int n) {
    int i = blockIdx.x * 256 + threadIdx.x;
    if (i < n) p[i] = 0;
}

// count in-degree AND capture each edge's rank within its dst bucket
__global__ void k_count(const int* __restrict__ ei, int* __restrict__ counts,
                        int* __restrict__ rank, int E) {
    int e = blockIdx.x * 256 + threadIdx.x;
    if (e < E) rank[e] = atomicAdd(&counts[ei[(size_t)E + e]], 1);
}

__global__ void k_dinv(const int* __restrict__ counts, float* dinv, int n) {
    int i = blockIdx.x * 256 + threadIdx.x;
    if (i < n) dinv[i] = rsqrtf((float)(counts[i] + 1));  // +1 self-loop
}

// phase A: per-block reduce of counts
__global__ __launch_bounds__(256) void k_scan_block(const int* __restrict__ counts,
                                                    int* __restrict__ bsums, int n) {
    __shared__ int red[256];
    int tid = threadIdx.x;
    int base = blockIdx.x * SCAN_CHUNK + tid * 8;
    int s = 0;
#pragma unroll
    for (int i = 0; i < 8; ++i) {
        int idx = base + i;
        s += (idx < n) ? counts[idx] : 0;
    }
    red[tid] = s;
    __syncthreads();
    for (int off = 128; off; off >>= 1) {
        if (tid < off) red[tid] += red[tid + off];
        __syncthreads();
    }
    if (tid == 0) bsums[blockIdx.x] = red[0];
}

// phase B: exclusive scan of block sums (nb <= 64), single block
__global__ void k_scan_sums(int* bsums, int nb) {
    __shared__ int ts[64];
    int tid = threadIdx.x;
    if (tid < 64) ts[tid] = (tid < nb) ? bsums[tid] : 0;
    __syncthreads();
    if (tid == 0) {
        int run = 0;
        for (int i = 0; i < nb; ++i) { int t = ts[i]; ts[i] = run; run += t; }
    }
    __syncthreads();
    if (tid < nb) bsums[tid] = ts[tid];
}

// phase C: full exclusive scan -> rowptr; rowptr[n]=E
__global__ __launch_bounds__(256) void k_scan_final(const int* __restrict__ counts,
                                                    const int* __restrict__ bsums,
                                                    int* __restrict__ rowptr, int n) {
    __shared__ int ts[256];
    int tid = threadIdx.x;
    int base0 = blockIdx.x * SCAN_CHUNK + tid * 8;
    int v[8], c[8];
    int s = 0;
#pragma unroll
    for (int i = 0; i < 8; ++i) {
        int idx = base0 + i;
        c[i] = (idx < n) ? counts[idx] : 0;
        v[i] = s;
        s += c[i];
    }
    ts[tid] = s;
    __syncthreads();
    for (int off = 1; off < 256; off <<= 1) {
        int t = (tid >= off) ? ts[tid - off] : 0;
        __syncthreads();
        if (tid >= off) ts[tid] += t;
        __syncthreads();
    }
    int texcl = ts[tid] - s;
    int base = bsums[blockIdx.x] + texcl;
#pragma unroll
    for (int i = 0; i < 8; ++i) {
        int idx = base0 + i;
        if (idx < n) {
            int val = base + v[i];
            rowptr[idx] = val;
            if (idx == n - 1) rowptr[n] = val + c[i];
        }
    }
}

// placement, atomic-free: col[rowptr[dst]+rank[e]] = src
__global__ void k_build(const int* __restrict__ ei, const int* __restrict__ rank,
                        const int* __restrict__ rowptr, int* __restrict__ col, int E) {
    int e = blockIdx.x * 256 + threadIdx.x;
    if (e >= E) return;
    int src = ei[e];
    int dst = ei[(size_t)E + e];
    col[rowptr[dst] + rank[e]] = src;
}

// ---------------- GEMM: H(fp16) = dinv * (A @ W) ----------------
// Async global_load_lds staging (width=16), double-buffered LDS, 1 barrier/tile.
// LDS strides UNPADDED (32 / 64 floats) -- required for lane-contiguous deposit.
template<int K>
__global__ __launch_bounds__(256) void k_gemm(
    const float* __restrict__ A, const float* __restrict__ W,
    const float* __restrict__ dinv, __half* __restrict__ H, int M)
{
    const int BM = 128, BK = 32;
    __shared__ float As[2 * BM * BK];    // [buf][m][k], stride 32
    __shared__ float Ws[2 * BK * NFEAT]; // [buf][k][n], stride 64

    int tid  = threadIdx.x;
    int w    = tid >> 6;
    int lane = tid & 63;
    int tx = tid & 15;
    int ty = tid >> 4;
    int m0 = blockIdx.x * BM;

    int a_ml = lane >> 3;
    int a_k  = (lane & 7) << 2;
    int w_kl = lane >> 4;
    int w_n  = (lane & 15) << 2;

    auto stage = [&](int k0, int buf) {
#pragma unroll
        for (int rep = 0; rep < 4; ++rep) {
            int c = w * 4 + rep;
            int row = m0 + c * 8 + a_ml;
            if (row > M - 1) row = M - 1;       // clamp: garbage rows never stored
            gll16(A + (size_t)row * K + k0 + a_k,
                  &As[buf * (BM * BK) + c * 256]);
        }
#pragma unroll
        for (int rep = 0; rep < 2; ++rep) {
            int c = w * 2 + rep;
            int kk = k0 + c * 4 + w_kl;
            gll16(W + (size_t)kk * NFEAT + w_n,
                  &Ws[buf * (BK * NFEAT) + c * 256]);
        }
    };

    float4 acc[8];
#pragma unroll
    for (int i = 0; i < 8; ++i) acc[i] = make_float4(0.f, 0.f, 0.f, 0.f);

    stage(0, 0);
    const int T = K / BK;
    for (int kt = 0; kt < T; ++kt) {
        __syncthreads();
        if (kt + 1 < T) stage((kt + 1) * BK, (kt + 1) & 1);
        const float* As_ = &As[(kt & 1) * (BM * BK)];
        const float* Ws_ = &Ws[(kt & 1) * (BK * NFEAT)];
#pragma unroll
        for (int kg = 0; kg < BK; kg += 4) {
            float4 w0 = *(const float4*)&Ws_[(kg + 0) * NFEAT + tx * 4];
            float4 w1 = *(const float4*)&Ws_[(kg + 1) * NFEAT + tx * 4];
            float4 w2 = *(const float4*)&Ws_[(kg + 2) * NFEAT + tx * 4];
            float4 w3 = *(const float4*)&Ws_[(kg + 3) * NFEAT + tx * 4];
#pragma unroll
            for (int i = 0; i < 8; ++i) {
                float4 a = *(const float4*)&As_[(i * 16 + ty) * BK + kg];
                acc[i].x = fmaf(a.x, w0.x, acc[i].x);
                acc[i].y = fmaf(a.x, w0.y, acc[i].y);
                acc[i].z = fmaf(a.x, w0.z, acc[i].z);
                acc[i].w = fmaf(a.x, w0.w, acc[i].w);
                acc[i].x = fmaf(a.y, w1.x, acc[i].x);
                acc[i].y = fmaf(a.y, w1.y, acc[i].y);
                acc[i].z = fmaf(a.y, w1.z, acc[i].z);
                acc[i].w = fmaf(a.y, w1.w, acc[i].w);
                acc[i].x = fmaf(a.z, w2.x, acc[i].x);
                acc[i].y = fmaf(a.z, w2.y, acc[i].y);
                acc[i].z = fmaf(a.z, w2.z, acc[i].z);
                acc[i].w = fmaf(a.z, w2.w, acc[i].w);
                acc[i].x = fmaf(a.w, w3.x, acc[i].x);
                acc[i].y = fmaf(a.w, w3.y, acc[i].y);
                acc[i].z = fmaf(a.w, w3.z, acc[i].z);
                acc[i].w = fmaf(a.w, w3.w, acc[i].w);
            }
        }
        __syncthreads();
    }

    // epilogue: H = fp16(dinv[row] * acc)  (pre-scaled; halves gather bytes)
#pragma unroll
    for (int i = 0; i < 8; ++i) {
        int row = m0 + i * 16 + ty;
        if (row < M) {
            float di = dinv[row];
            __half2 lo = __float22half2_rn(make_float2(di * acc[i].x, di * acc[i].y));
            __half2 hi = __float22half2_rn(make_float2(di * acc[i].z, di * acc[i].w));
            uint2 u;
            u.x = __builtin_bit_cast(unsigned int, lo);
            u.y = __builtin_bit_cast(unsigned int, hi);
            *(uint2*)(H + (size_t)row * NFEAT + tx * 4) = u;  // 8B aligned
        }
    }
}

// ---------------- CSR gather-aggregate: 1 slot = 1 row ------------------------
// 8 slots/wave x 8 lanes x uint4(16B) = one 128B fp16 row per slot per instr.
// No cross-slot reduction; setup/epilogue amortized over 8 rows/wave.
// t = relu(bias + dinv[r]*(h[r] + sum_j h[col[j]]));  FC: out[r] = t @ Wfc + bfc
template<bool FC>
__global__ __launch_bounds__(256) void k_aggr(
    const __half* __restrict__ h, const int* __restrict__ rowptr,
    const int* __restrict__ col, const float* __restrict__ dinv,
    const float* __restrict__ bias, const float* __restrict__ Wfc,
    const float* __restrict__ bfc, float* __restrict__ out, int n)
{
    __shared__ float Wl[NFEAT * 11 + 11];
    int tid = threadIdx.x;
    if (FC) {
        for (int i = tid; i < NFEAT * 11; i += 256) Wl[i] = Wfc[i];
        if (tid < 11) Wl[NFEAT * 11 + tid] = bfc[tid];
        __syncthreads();
    }
    int lane = tid & 63;
    int li = lane & 7;            // lane in slot
    int fi = li << 3;             // feature base (8 halves = 16B)
    int r = blockIdx.x * 32 + ((tid >> 6) << 3) + (lane >> 3);  // 32 rows/block
    bool valid = r < n;

    int beg = 0, end = 0;
    if (valid) { beg = rowptr[r]; end = rowptr[r + 1]; }

    const __half* hp = h + fi;
    auto ld = [&](int src) { return *(const uint4*)(hp + (size_t)src * NFEAT); };

    float a0 = 0.f, a1 = 0.f, a2 = 0.f, a3 = 0.f,
          a4 = 0.f, a5 = 0.f, a6 = 0.f, a7 = 0.f;
    auto addu = [&](uint4 u) {
        float2 f0 = __half22float2(bch(u.x));
        float2 f1 = __half22float2(bch(u.y));
        float2 f2 = __half22float2(bch(u.z));
        float2 f3 = __half22float2(bch(u.w));
        a0 += f0.x; a1 += f0.y; a2 += f1.x; a3 += f1.y;
        a4 += f2.x; a5 += f2.y; a6 += f3.x; a7 += f3.y;
    };

    if (valid) addu(ld(r));       // self-loop
    int j = beg;
    for (; j + 1 < end; j += 2) {           // 2 gathers in flight per slot (16/wave)
        uint4 u0 = ld(col[j]);
        uint4 u1 = ld(col[j + 1]);
        // pairwise fp16 fold: 4 pk-adds, then one fp32 convert+acc
        uint4 s;
        s.x = __builtin_bit_cast(unsigned int, __hadd2(bch(u0.x), bch(u1.x)));
        s.y = __builtin_bit_cast(unsigned int, __hadd2(bch(u0.y), bch(u1.y)));
        s.z = __builtin_bit_cast(unsigned int, __hadd2(bch(u0.z), bch(u1.z)));
        s.w = __builtin_bit_cast(unsigned int, __hadd2(bch(u0.w), bch(u1.w)));
        addu(s);
    }
    if (j < end) addu(ld(col[j]));

    if (!valid) return;
    float di = dinv[r];
    float t0 = fmaxf(bias[fi + 0] + di * a0, 0.f);
    float t1 = fmaxf(bias[fi + 1] + di * a1, 0.f);
    float t2 = fmaxf(bias[fi + 2] + di * a2, 0.f);
    float t3 = fmaxf(bias[fi + 3] + di * a3, 0.f);
    float t4 = fmaxf(bias[fi + 4] + di * a4, 0.f);
    float t5 = fmaxf(bias[fi + 5] + di * a5, 0.f);
    float t6 = fmaxf(bias[fi + 6] + di * a6, 0.f);
    float t7 = fmaxf(bias[fi + 7] + di * a7, 0.f);

    if (!FC) {
        float4 lo = make_float4(t0, t1, t2, t3);
        float4 hi = make_float4(t4, t5, t6, t7);
        float* op = out + (size_t)r * NFEAT + fi;
        *(float4*)op = lo;
        *(float4*)(op + 4) = hi;
    } else {
#pragma unroll
        for (int c = 0; c < 11; ++c) {
            const float* wc = &Wl[fi * 11 + c];
            float p = t0 * wc[0] + t1 * wc[11] + t2 * wc[22] + t3 * wc[33]
                    + t4 * wc[44] + t5 * wc[55] + t6 * wc[66] + t7 * wc[77];
            p += __shfl_xor(p, 1, 64);
            p += __shfl_xor(p, 2, 64);
            p += __shfl_xor(p, 4, 64);
            if (li == 0) out[(size_t)r * 11 + c] = p + Wl[NFEAT * 11 + c];
        }
    }
}

extern "C" void kernel_launch(void* const* d_in, const int* in_sizes, int n_in,
                              void* d_out, int out_size, void* d_ws, size_t ws_size,
                              hipStream_t stream) {
    const float* x   = (const float*)d_in[0];
    const int*   ei  = (const int*)d_in[1];
    const float* W1  = (const float*)d_in[2];
    const float* b1  = (const float*)d_in[3];
    const float* W2  = (const float*)d_in[4];
    const float* b2  = (const float*)d_in[5];
    const float* Wfc = (const float*)d_in[6];
    const float* bfc = (const float*)d_in[7];
    float* out = (float*)d_out;

    const int Fin = 256;
    int N = in_sizes[0] / Fin;      // 100000
    int E = in_sizes[1] / 2;        // 1600000

    char* ws = (char*)d_ws;
    size_t off = 0;
    auto alloc = [&](size_t bytes) { void* p = ws + off; off = (off + bytes + 255) & ~(size_t)255; return p; };
    int*    counts = (int*)   alloc((size_t)N * 4);
    int*    rowptr = (int*)   alloc((size_t)(N + 1) * 4);
    float*  dinv   = (float*) alloc((size_t)N * 4);
    int*    bsums  = (int*)   alloc(64 * 4);
    int*    rank   = (int*)   alloc((size_t)E * 4);
    int*    col    = (int*)   alloc((size_t)E * 4);
    __half* A      = (__half*)alloc((size_t)N * NFEAT * 2);  // h buffer (fp16)
    float*  B      = (float*) alloc((size_t)N * NFEAT * 4);  // relu(out1) buffer

    int gN = (N + 255) / 256;
    int gE = (E + 255) / 256;
    int gb = (N + 127) / 128;
    int gA = (N + 31) / 32;        // 32 rows per block (8 slots x 4 waves)
    int nb = (N + SCAN_CHUNK - 1) / SCAN_CHUNK;   // 49 <= 64

    // CSR build (atomic-free placement via ranks)
    k_zero<<<gN, 256, 0, stream>>>(counts, N);
    k_count<<<gE, 256, 0, stream>>>(ei, counts, rank, E);
    k_dinv<<<gN, 256, 0, stream>>>(counts, dinv, N);
    k_scan_block<<<nb, 256, 0, stream>>>(counts, bsums, N);
    k_scan_sums<<<1, 64, 0, stream>>>(bsums, nb);
    k_scan_final<<<nb, 256, 0, stream>>>(counts, bsums, rowptr, N);
    k_build<<<gE, 256, 0, stream>>>(ei, rank, rowptr, col, E);

    // layer 1: h1=fp16(dinv*(x@W1)); B = relu(b1 + dinv*(h1[r]+sum h1[col]))
    k_gemm<256><<<gb, 256, 0, stream>>>(x, W1, dinv, A, N);
    k_aggr<false><<<gA, 256, 0, stream>>>(A, rowptr, col, dinv, b1, nullptr, nullptr, B, N);

    // layer 2: h2=fp16(dinv*(B@W2)); fused aggr+relu+FC -> out
    k_gemm<64><<<gb, 256, 0, stream>>>(B, W2, dinv, A, N);
    k_aggr<true><<<gA, 256, 0, stream>>>(A, rowptr, col, dinv, b2, Wfc, bfc, out, N);
}

// Round 9
// 386.705 us; speedup vs baseline: 2.8524x; 1.0666x over previous
//
#include <hip/hip_runtime.h>
#include <hip/hip_fp16.h>

#define NFEAT 64
#define SCAN_CHUNK 2048   // 256 threads x 8

typedef _Float16 half8 __attribute__((ext_vector_type(8)));
typedef float f32x4 __attribute__((ext_vector_type(4)));

// ---------------- async global->LDS helper (16B per lane, wave-uniform LDS base) ---
__device__ __forceinline__ void gll16(const float* g, float* l) {
    __builtin_amdgcn_global_load_lds(
        (const __attribute__((address_space(1))) unsigned int*)g,
        (__attribute__((address_space(3))) unsigned int*)l, 16, 0, 0);
}

__device__ __forceinline__ __half2 bch(unsigned int u) {
    return __builtin_bit_cast(__half2, u);
}

// ---------------- degree / CSR build ----------------
__global__ void k_zero(int* p, int n) {
    int i = blockIdx.x * 256 + threadIdx.x;
    if (i < n) p[i] = 0;
}

__global__ void k_count(const int* __restrict__ ei, int* __restrict__ counts,
                        int* __restrict__ rank, int E) {
    int e = blockIdx.x * 256 + threadIdx.x;
    if (e < E) rank[e] = atomicAdd(&counts[ei[(size_t)E + e]], 1);
}

__global__ void k_dinv(const int* __restrict__ counts, float* dinv, int n) {
    int i = blockIdx.x * 256 + threadIdx.x;
    if (i < n) dinv[i] = rsqrtf((float)(counts[i] + 1));  // +1 self-loop
}

__global__ __launch_bounds__(256) void k_scan_block(const int* __restrict__ counts,
                                                    int* __restrict__ bsums, int n) {
    __shared__ int red[256];
    int tid = threadIdx.x;
    int base = blockIdx.x * SCAN_CHUNK + tid * 8;
    int s = 0;
#pragma unroll
    for (int i = 0; i < 8; ++i) {
        int idx = base + i;
        s += (idx < n) ? counts[idx] : 0;
    }
    red[tid] = s;
    __syncthreads();
    for (int off = 128; off; off >>= 1) {
        if (tid < off) red[tid] += red[tid + off];
        __syncthreads();
    }
    if (tid == 0) bsums[blockIdx.x] = red[0];
}

__global__ void k_scan_sums(int* bsums, int nb) {
    __shared__ int ts[64];
    int tid = threadIdx.x;
    if (tid < 64) ts[tid] = (tid < nb) ? bsums[tid] : 0;
    __syncthreads();
    if (tid == 0) {
        int run = 0;
        for (int i = 0; i < nb; ++i) { int t = ts[i]; ts[i] = run; run += t; }
    }
    __syncthreads();
    if (tid < nb) bsums[tid] = ts[tid];
}

__global__ __launch_bounds__(256) void k_scan_final(const int* __restrict__ counts,
                                                    const int* __restrict__ bsums,
                                                    int* __restrict__ rowptr, int n) {
    __shared__ int ts[256];
    int tid = threadIdx.x;
    int base0 = blockIdx.x * SCAN_CHUNK + tid * 8;
    int v[8], c[8];
    int s = 0;
#pragma unroll
    for (int i = 0; i < 8; ++i) {
        int idx = base0 + i;
        c[i] = (idx < n) ? counts[idx] : 0;
        v[i] = s;
        s += c[i];
    }
    ts[tid] = s;
    __syncthreads();
    for (int off = 1; off < 256; off <<= 1) {
        int t = (tid >= off) ? ts[tid - off] : 0;
        __syncthreads();
        if (tid >= off) ts[tid] += t;
        __syncthreads();
    }
    int texcl = ts[tid] - s;
    int base = bsums[blockIdx.x] + texcl;
#pragma unroll
    for (int i = 0; i < 8; ++i) {
        int idx = base0 + i;
        if (idx < n) {
            int val = base + v[i];
            rowptr[idx] = val;
            if (idx == n - 1) rowptr[n] = val + c[i];
        }
    }
}

__global__ void k_build(const int* __restrict__ ei, const int* __restrict__ rank,
                        const int* __restrict__ rowptr, int* __restrict__ col, int E) {
    int e = blockIdx.x * 256 + threadIdx.x;
    if (e >= E) return;
    int src = ei[e];
    int dst = ei[(size_t)E + e];
    col[rowptr[dst] + rank[e]] = src;
}

// ---------------- W transpose+convert: Wt[n][k] = fp16(W[k][n]) ----------------
__global__ void k_cvtW(const float* __restrict__ W, __half* __restrict__ Wt, int K) {
    int idx = blockIdx.x * 256 + threadIdx.x;
    if (idx >= 64 * K) return;
    int n = idx / K;
    int k = idx % K;
    Wt[idx] = __float2half(W[(size_t)k * NFEAT + n]);
}

// ---------------- MFMA GEMM: H(fp16) = dinv * (A @ W) --------------------------
// A fp32 staged via global_load_lds with XOR-swizzled chunk layout (conflict-free
// fragment reads); split-precision: A = hi + lo in fp16, 2 MFMAs -> ~fp32 accuracy.
// Wt fp16 [64][K] loaded once into padded LDS.
template<int K>
__global__ __launch_bounds__(256) void k_gemm(
    const float* __restrict__ A, const __half* __restrict__ Wt,
    const float* __restrict__ dinv, __half* __restrict__ H, int M)
{
    const int BM = 128, BK = 32;
    const int WROW = K + 8;               // halves per Wlds row (pad: 2-way, free)
    __shared__ float As[2 * BM * BK];     // [buf][chunk-swizzled], chunk=4 floats
    __shared__ __half Wlds[64 * WROW];

    int tid = threadIdx.x;
    int w = tid >> 6, lane = tid & 63;
    int q = lane >> 4, n16 = lane & 15;
    int m0 = blockIdx.x * BM;

    auto stage = [&](int k0, int buf) {
#pragma unroll
        for (int rep = 0; rep < 4; ++rep) {
            int cb = (w * 4 + rep) * 64;          // chunk base (wave-uniform)
            int s = cb + lane;                    // chunk index 0..1023
            int m = s >> 3;                       // tile row 0..127
            int kk = (s & 7) ^ (m & 7);           // XOR swizzle
            int row = m0 + m; if (row > M - 1) row = M - 1;  // clamp, never stored
            gll16(A + (size_t)row * K + k0 + kk * 4,
                  &As[buf * (BM * BK) + cb * 4]);
        }
    };

    stage(0, 0);   // async; W-load below overlaps

    // one-time Wt load (16B per thread per iter)
    for (int idx = tid; idx < 64 * (K / 8); idx += 256) {
        int row = idx / (K / 8);
        int c = idx % (K / 8);
        *(uint4*)&Wlds[row * WROW + c * 8] = *(const uint4*)&Wt[(size_t)row * K + c * 8];
    }

    f32x4 acc[2][4];
#pragma unroll
    for (int t = 0; t < 2; ++t)
#pragma unroll
        for (int nt = 0; nt < 4; ++nt) acc[t][nt] = (f32x4)(0.f);

    const int T = K / BK;
    for (int kt = 0; kt < T; ++kt) {
        __syncthreads();                      // tile kt deposited + Wlds ready
        if (kt + 1 < T) stage((kt + 1) * BK, (kt + 1) & 1);
        const float* As_ = &As[(kt & 1) * (BM * BK)];

        // A fragments: a[j] = A[m = n16][k = q*8+j], split hi/lo
        half8 ahi[2], alo[2];
#pragma unroll
        for (int t = 0; t < 2; ++t) {
            int ml = w * 32 + t * 16 + n16;
            int e0 = (2 * q) ^ (ml & 7);
            int e1 = (2 * q + 1) ^ (ml & 7);
            float4 f0 = *(const float4*)&As_[(ml * 8 + e0) * 4];
            float4 f1 = *(const float4*)&As_[(ml * 8 + e1) * 4];
            float fv[8] = {f0.x, f0.y, f0.z, f0.w, f1.x, f1.y, f1.z, f1.w};
#pragma unroll
            for (int j = 0; j < 8; ++j) {
                _Float16 hi = (_Float16)fv[j];
                ahi[t][j] = hi;
                alo[t][j] = (_Float16)(fv[j] - (float)hi);
            }
        }
        // B fragments: b[j] = W[k = kt*32 + q*8+j][n = nt*16+n16]
#pragma unroll
        for (int nt = 0; nt < 4; ++nt) {
            uint4 u = *(const uint4*)&Wlds[(nt * 16 + n16) * WROW + kt * BK + q * 8];
            half8 b = __builtin_bit_cast(half8, u);
            acc[0][nt] = __builtin_amdgcn_mfma_f32_16x16x32_f16(ahi[0], b, acc[0][nt], 0, 0, 0);
            acc[0][nt] = __builtin_amdgcn_mfma_f32_16x16x32_f16(alo[0], b, acc[0][nt], 0, 0, 0);
            acc[1][nt] = __builtin_amdgcn_mfma_f32_16x16x32_f16(ahi[1], b, acc[1][nt], 0, 0, 0);
            acc[1][nt] = __builtin_amdgcn_mfma_f32_16x16x32_f16(alo[1], b, acc[1][nt], 0, 0, 0);
        }
        __syncthreads();
    }

    // epilogue: D[row = q*4+reg][col = n16]; H = fp16(dinv*acc)
#pragma unroll
    for (int t = 0; t < 2; ++t) {
#pragma unroll
        for (int reg = 0; reg < 4; ++reg) {
            int row = m0 + w * 32 + t * 16 + q * 4 + reg;
            if (row < M) {
                float di = dinv[row];
#pragma unroll
                for (int nt = 0; nt < 4; ++nt)
                    H[(size_t)row * NFEAT + nt * 16 + n16] =
                        __float2half(di * acc[t][nt][reg]);
            }
        }
    }
}

// ---------------- CSR gather-aggregate: 1 slot = 1 row ------------------------
template<bool FC>
__global__ __launch_bounds__(256) void k_aggr(
    const __half* __restrict__ h, const int* __restrict__ rowptr,
    const int* __restrict__ col, const float* __restrict__ dinv,
    const float* __restrict__ bias, const float* __restrict__ Wfc,
    const float* __restrict__ bfc, float* __restrict__ out, int n)
{
    __shared__ float Wl[NFEAT * 11 + 11];
    int tid = threadIdx.x;
    if (FC) {
        for (int i = tid; i < NFEAT * 11; i += 256) Wl[i] = Wfc[i];
        if (tid < 11) Wl[NFEAT * 11 + tid] = bfc[tid];
        __syncthreads();
    }
    int lane = tid & 63;
    int li = lane & 7;
    int fi = li << 3;
    int r = blockIdx.x * 32 + ((tid >> 6) << 3) + (lane >> 3);
    bool valid = r < n;

    int beg = 0, end = 0;
    if (valid) { beg = rowptr[r]; end = rowptr[r + 1]; }

    const __half* hp = h + fi;
    auto ld = [&](int src) { return *(const uint4*)(hp + (size_t)src * NFEAT); };

    float a0 = 0.f, a1 = 0.f, a2 = 0.f, a3 = 0.f,
          a4 = 0.f, a5 = 0.f, a6 = 0.f, a7 = 0.f;
    auto addu = [&](uint4 u) {
        float2 f0 = __half22float2(bch(u.x));
        float2 f1 = __half22float2(bch(u.y));
        float2 f2 = __half22float2(bch(u.z));
        float2 f3 = __half22float2(bch(u.w));
        a0 += f0.x; a1 += f0.y; a2 += f1.x; a3 += f1.y;
        a4 += f2.x; a5 += f2.y; a6 += f3.x; a7 += f3.y;
    };

    if (valid) addu(ld(r));
    int j = beg;
    for (; j + 1 < end; j += 2) {
        uint4 u0 = ld(col[j]);
        uint4 u1 = ld(col[j + 1]);
        uint4 s;
        s.x = __builtin_bit_cast(unsigned int, __hadd2(bch(u0.x), bch(u1.x)));
        s.y = __builtin_bit_cast(unsigned int, __hadd2(bch(u0.y), bch(u1.y)));
        s.z = __builtin_bit_cast(unsigned int, __hadd2(bch(u0.z), bch(u1.z)));
        s.w = __builtin_bit_cast(unsigned int, __hadd2(bch(u0.w), bch(u1.w)));
        addu(s);
    }
    if (j < end) addu(ld(col[j]));

    if (!valid) return;
    float di = dinv[r];
    float t0 = fmaxf(bias[fi + 0] + di * a0, 0.f);
    float t1 = fmaxf(bias[fi + 1] + di * a1, 0.f);
    float t2 = fmaxf(bias[fi + 2] + di * a2, 0.f);
    float t3 = fmaxf(bias[fi + 3] + di * a3, 0.f);
    float t4 = fmaxf(bias[fi + 4] + di * a4, 0.f);
    float t5 = fmaxf(bias[fi + 5] + di * a5, 0.f);
    float t6 = fmaxf(bias[fi + 6] + di * a6, 0.f);
    float t7 = fmaxf(bias[fi + 7] + di * a7, 0.f);

    if (!FC) {
        float4 lo = make_float4(t0, t1, t2, t3);
        float4 hi = make_float4(t4, t5, t6, t7);
        float* op = out + (size_t)r * NFEAT + fi;
        *(float4*)op = lo;
        *(float4*)(op + 4) = hi;
    } else {
#pragma unroll
        for (int c = 0; c < 11; ++c) {
            const float* wc = &Wl[fi * 11 + c];
            float p = t0 * wc[0] + t1 * wc[11] + t2 * wc[22] + t3 * wc[33]
                    + t4 * wc[44] + t5 * wc[55] + t6 * wc[66] + t7 * wc[77];
            p += __shfl_xor(p, 1, 64);
            p += __shfl_xor(p, 2, 64);
            p += __shfl_xor(p, 4, 64);
            if (li == 0) out[(size_t)r * 11 + c] = p + Wl[NFEAT * 11 + c];
        }
    }
}

extern "C" void kernel_launch(void* const* d_in, const int* in_sizes, int n_in,
                              void* d_out, int out_size, void* d_ws, size_t ws_size,
                              hipStream_t stream) {
    const float* x   = (const float*)d_in[0];
    const int*   ei  = (const int*)d_in[1];
    const float* W1  = (const float*)d_in[2];
    const float* b1  = (const float*)d_in[3];
    const float* W2  = (const float*)d_in[4];
    const float* b2  = (const float*)d_in[5];
    const float* Wfc = (const float*)d_in[6];
    const float* bfc = (const float*)d_in[7];
    float* out = (float*)d_out;

    const int Fin = 256;
    int N = in_sizes[0] / Fin;      // 100000
    int E = in_sizes[1] / 2;        // 1600000

    char* ws = (char*)d_ws;
    size_t off = 0;
    auto alloc = [&](size_t bytes) { void* p = ws + off; off = (off + bytes + 255) & ~(size_t)255; return p; };
    int*    counts = (int*)   alloc((size_t)N * 4);
    int*    rowptr = (int*)   alloc((size_t)(N + 1) * 4);
    float*  dinv   = (float*) alloc((size_t)N * 4);
    int*    bsums  = (int*)   alloc(64 * 4);
    int*    rank   = (int*)   alloc((size_t)E * 4);
    int*    col    = (int*)   alloc((size_t)E * 4);
    __half* Wt1    = (__half*)alloc((size_t)64 * 256 * 2);
    __half* Wt2    = (__half*)alloc((size_t)64 * 64 * 2);
    __half* A      = (__half*)alloc((size_t)N * NFEAT * 2);  // h buffer (fp16)
    float*  B      = (float*) alloc((size_t)N * NFEAT * 4);  // relu(out1) buffer

    int gN = (N + 255) / 256;
    int gE = (E + 255) / 256;
    int gb = (N + 127) / 128;
    int gA = (N + 31) / 32;
    int nb = (N + SCAN_CHUNK - 1) / SCAN_CHUNK;   // 49 <= 64

    // CSR build (atomic-free placement via ranks) + weight transposes
    k_zero<<<gN, 256, 0, stream>>>(counts, N);
    k_count<<<gE, 256, 0, stream>>>(ei, counts, rank, E);
    k_cvtW<<<(64 * 256 + 255) / 256, 256, 0, stream>>>(W1, Wt1, 256);
    k_cvtW<<<(64 * 64 + 255) / 256, 256, 0, stream>>>(W2, Wt2, 64);
    k_dinv<<<gN, 256, 0, stream>>>(counts, dinv, N);
    k_scan_block<<<nb, 256, 0, stream>>>(counts, bsums, N);
    k_scan_sums<<<1, 64, 0, stream>>>(bsums, nb);
    k_scan_final<<<nb, 256, 0, stream>>>(counts, bsums, rowptr, N);
    k_build<<<gE, 256, 0, stream>>>(ei, rank, rowptr, col, E);

    // layer 1: h1=fp16(dinv*(x@W1)); B = relu(b1 + dinv*(h1[r]+sum h1[col]))
    k_gemm<256><<<gb, 256, 0, stream>>>(x, Wt1, dinv, A, N);
    k_aggr<false><<<gA, 256, 0, stream>>>(A, rowptr, col, dinv, b1, nullptr, nullptr, B, N);

    // layer 2: h2=fp16(dinv*(B@W2)); fused aggr+relu+FC -> out
    k_gemm<64><<<gb, 256, 0, stream>>>(B, Wt2, dinv, A, N);
    k_aggr<true><<<gA, 256, 0, stream>>>(A, rowptr, col, dinv, b2, Wfc, bfc, out, N);
}

// Round 10
// 354.943 us; speedup vs baseline: 3.1077x; 1.0895x over previous
//
#include <hip/hip_runtime.h>
#include <hip/hip_fp16.h>

#define NFEAT 64
#define SCAN_CHUNK 2048   // 256 threads x 8

typedef _Float16 half8 __attribute__((ext_vector_type(8)));
typedef float f32x4 __attribute__((ext_vector_type(4)));

// ---------------- async global->LDS helper (16B per lane, wave-uniform LDS base) ---
__device__ __forceinline__ void gll16(const float* g, float* l) {
    __builtin_amdgcn_global_load_lds(
        (const __attribute__((address_space(1))) unsigned int*)g,
        (__attribute__((address_space(3))) unsigned int*)l, 16, 0, 0);
}

__device__ __forceinline__ __half2 bch(unsigned int u) {
    return __builtin_bit_cast(__half2, u);
}

// ---------------- W transpose+convert: Wt[n][k] = fp16(W[k][n]) ----------------
__global__ void k_cvtW(const float* __restrict__ W, __half* __restrict__ Wt, int K) {
    int idx = blockIdx.x * 256 + threadIdx.x;
    if (idx >= 64 * K) return;
    int n = idx / K;
    int k = idx % K;
    Wt[idx] = __float2half(W[(size_t)k * NFEAT + n]);
}

// ---------------- FUSED: MFMA GEMM  +  degree-count/rank -----------------------
// CNT: blocks bid%3!=2 run the count path (2:1 interleave matches 1563:782),
// hiding atomic write-through latency under the MFMA blocks.
// GEMM: H(fp16) = A @ W (unscaled when !SCALE; dinv applied later in build_scale).
template<int K, bool SCALE, bool CNT>
__global__ __launch_bounds__(256) void k_gemm_x(
    const float* __restrict__ A, const __half* __restrict__ Wt,
    const float* __restrict__ dinv, __half* __restrict__ H, int M,
    const int* __restrict__ eiDst, int* __restrict__ counts,
    int* __restrict__ rank, int E)
{
    int tid = threadIdx.x;
    int gemmIdx;
    if (CNT) {
        int bid = blockIdx.x;
        if (bid % 3 != 2) {
            // ---- count path: 4 edges/thread, batched atomics ----
            int cIdx = bid - (bid + 1) / 3;
            int t = (cIdx * 256 + tid) * 4;
            if (t + 3 < E) {
                int4 d = *(const int4*)(eiDst + t);
                int r0 = atomicAdd(&counts[d.x], 1);
                int r1 = atomicAdd(&counts[d.y], 1);
                int r2 = atomicAdd(&counts[d.z], 1);
                int r3 = atomicAdd(&counts[d.w], 1);
                *(int4*)(rank + t) = make_int4(r0, r1, r2, r3);
            } else {
                for (int e = t; e < E; ++e)
                    rank[e] = atomicAdd(&counts[eiDst[e]], 1);
            }
            return;
        }
        gemmIdx = bid / 3;
    } else {
        gemmIdx = blockIdx.x;
    }

    const int BM = 128, BK = 32;
    const int WROW = K + 8;               // halves per Wlds row (pad: 2-way, free)
    __shared__ float As[2 * BM * BK];     // [buf][chunk-swizzled], chunk=4 floats
    __shared__ __half Wlds[64 * WROW];

    int w = tid >> 6, lane = tid & 63;
    int q = lane >> 4, n16 = lane & 15;
    int m0 = gemmIdx * BM;

    auto stage = [&](int k0, int buf) {
#pragma unroll
        for (int rep = 0; rep < 4; ++rep) {
            int cb = (w * 4 + rep) * 64;          // chunk base (wave-uniform)
            int s = cb + lane;                    // chunk index 0..1023
            int m = s >> 3;                       // tile row 0..127
            int kk = (s & 7) ^ (m & 7);           // XOR swizzle
            int row = m0 + m; if (row > M - 1) row = M - 1;  // clamp, never stored
            gll16(A + (size_t)row * K + k0 + kk * 4,
                  &As[buf * (BM * BK) + cb * 4]);
        }
    };

    stage(0, 0);   // async; W-load below overlaps

    for (int idx = tid; idx < 64 * (K / 8); idx += 256) {
        int row = idx / (K / 8);
        int c = idx % (K / 8);
        *(uint4*)&Wlds[row * WROW + c * 8] = *(const uint4*)&Wt[(size_t)row * K + c * 8];
    }

    f32x4 acc[2][4];
#pragma unroll
    for (int t = 0; t < 2; ++t)
#pragma unroll
        for (int nt = 0; nt < 4; ++nt) acc[t][nt] = (f32x4)(0.f);

    const int T = K / BK;
    for (int kt = 0; kt < T; ++kt) {
        __syncthreads();                      // tile kt deposited + Wlds ready
        if (kt + 1 < T) stage((kt + 1) * BK, (kt + 1) & 1);
        const float* As_ = &As[(kt & 1) * (BM * BK)];

        half8 ahi[2], alo[2];
#pragma unroll
        for (int t = 0; t < 2; ++t) {
            int ml = w * 32 + t * 16 + n16;
            int e0 = (2 * q) ^ (ml & 7);
            int e1 = (2 * q + 1) ^ (ml & 7);
            float4 f0 = *(const float4*)&As_[(ml * 8 + e0) * 4];
            float4 f1 = *(const float4*)&As_[(ml * 8 + e1) * 4];
            float fv[8] = {f0.x, f0.y, f0.z, f0.w, f1.x, f1.y, f1.z, f1.w};
#pragma unroll
            for (int j = 0; j < 8; ++j) {
                _Float16 hi = (_Float16)fv[j];
                ahi[t][j] = hi;
                alo[t][j] = (_Float16)(fv[j] - (float)hi);
            }
        }
#pragma unroll
        for (int nt = 0; nt < 4; ++nt) {
            uint4 u = *(const uint4*)&Wlds[(nt * 16 + n16) * WROW + kt * BK + q * 8];
            half8 b = __builtin_bit_cast(half8, u);
            acc[0][nt] = __builtin_amdgcn_mfma_f32_16x16x32_f16(ahi[0], b, acc[0][nt], 0, 0, 0);
            acc[0][nt] = __builtin_amdgcn_mfma_f32_16x16x32_f16(alo[0], b, acc[0][nt], 0, 0, 0);
            acc[1][nt] = __builtin_amdgcn_mfma_f32_16x16x32_f16(ahi[1], b, acc[1][nt], 0, 0, 0);
            acc[1][nt] = __builtin_amdgcn_mfma_f32_16x16x32_f16(alo[1], b, acc[1][nt], 0, 0, 0);
        }
        __syncthreads();
    }

    // epilogue: D[row = q*4+reg][col = n16]
#pragma unroll
    for (int t = 0; t < 2; ++t) {
#pragma unroll
        for (int reg = 0; reg < 4; ++reg) {
            int row = m0 + w * 32 + t * 16 + q * 4 + reg;
            if (row < M) {
                float di = SCALE ? dinv[row] : 1.0f;
#pragma unroll
                for (int nt = 0; nt < 4; ++nt)
                    H[(size_t)row * NFEAT + nt * 16 + n16] =
                        __float2half(di * acc[t][nt][reg]);
            }
        }
    }
}

// ---------------- FUSED: scan phase A + dinv ----------------------------------
__global__ __launch_bounds__(256) void k_dinv_scan(
    const int* __restrict__ counts, int* __restrict__ bsums,
    float* __restrict__ dinv, int n, int nbScan)
{
    __shared__ int red[256];
    int bid = blockIdx.x;
    int tid = threadIdx.x;
    if (bid < nbScan) {
        int base = bid * SCAN_CHUNK + tid * 8;
        int s = 0;
#pragma unroll
        for (int i = 0; i < 8; ++i) {
            int idx = base + i;
            s += (idx < n) ? counts[idx] : 0;
        }
        red[tid] = s;
        __syncthreads();
        for (int off = 128; off; off >>= 1) {
            if (tid < off) red[tid] += red[tid + off];
            __syncthreads();
        }
        if (tid == 0) bsums[bid] = red[0];
    } else {
        int i = (bid - nbScan) * 256 + tid;
        if (i < n) dinv[i] = rsqrtf((float)(counts[i] + 1));  // +1 self-loop
    }
}

__global__ void k_scan_sums(int* bsums, int nb) {
    __shared__ int ts[64];
    int tid = threadIdx.x;
    if (tid < 64) ts[tid] = (tid < nb) ? bsums[tid] : 0;
    __syncthreads();
    if (tid == 0) {
        int run = 0;
        for (int i = 0; i < nb; ++i) { int t = ts[i]; ts[i] = run; run += t; }
    }
    __syncthreads();
    if (tid < nb) bsums[tid] = ts[tid];
}

__global__ __launch_bounds__(256) void k_scan_final(const int* __restrict__ counts,
                                                    const int* __restrict__ bsums,
                                                    int* __restrict__ rowptr, int n) {
    __shared__ int ts[256];
    int tid = threadIdx.x;
    int base0 = blockIdx.x * SCAN_CHUNK + tid * 8;
    int v[8], c[8];
    int s = 0;
#pragma unroll
    for (int i = 0; i < 8; ++i) {
        int idx = base0 + i;
        c[i] = (idx < n) ? counts[idx] : 0;
        v[i] = s;
        s += c[i];
    }
    ts[tid] = s;
    __syncthreads();
    for (int off = 1; off < 256; off <<= 1) {
        int t = (tid >= off) ? ts[tid - off] : 0;
        __syncthreads();
        if (tid >= off) ts[tid] += t;
        __syncthreads();
    }
    int texcl = ts[tid] - s;
    int base = bsums[blockIdx.x] + texcl;
#pragma unroll
    for (int i = 0; i < 8; ++i) {
        int idx = base0 + i;
        if (idx < n) {
            int val = base + v[i];
            rowptr[idx] = val;
            if (idx == n - 1) rowptr[n] = val + c[i];
        }
    }
}

// ---------------- FUSED: CSR placement + deferred h *= dinv --------------------
__global__ __launch_bounds__(256) void k_build_scale(
    const int* __restrict__ ei, const int* __restrict__ rank,
    const int* __restrict__ rowptr, int* __restrict__ col, int E,
    __half* __restrict__ A, const float* __restrict__ dinv, int N, int gE)
{
    int bid = blockIdx.x;
    if (bid < gE) {
        int e = bid * 256 + threadIdx.x;
        if (e >= E) return;
        int src = ei[e];
        int dst = ei[(size_t)E + e];
        col[rowptr[dst] + rank[e]] = src;
    } else {
        int i = (bid - gE) * 256 + threadIdx.x;   // uint4 index (8 halves)
        if (i >= N * 8) return;
        float di = dinv[i >> 3];
        uint4* p = (uint4*)A + i;
        uint4 u = *p;
        auto sc = [&](unsigned int x) {
            float2 f = __half22float2(bch(x));
            return __builtin_bit_cast(unsigned int,
                   __float22half2_rn(make_float2(f.x * di, f.y * di)));
        };
        u.x = sc(u.x); u.y = sc(u.y); u.z = sc(u.z); u.w = sc(u.w);
        *p = u;
    }
}

// ---------------- CSR gather-aggregate: 1 slot = 1 row ------------------------
template<bool FC>
__global__ __launch_bounds__(256) void k_aggr(
    const __half* __restrict__ h, const int* __restrict__ rowptr,
    const int* __restrict__ col, const float* __restrict__ dinv,
    const float* __restrict__ bias, const float* __restrict__ Wfc,
    const float* __restrict__ bfc, float* __restrict__ out, int n)
{
    __shared__ float Wl[NFEAT * 11 + 11];
    int tid = threadIdx.x;
    if (FC) {
        for (int i = tid; i < NFEAT * 11; i += 256) Wl[i] = Wfc[i];
        if (tid < 11) Wl[NFEAT * 11 + tid] = bfc[tid];
        __syncthreads();
    }
    int lane = tid & 63;
    int li = lane & 7;
    int fi = li << 3;
    int r = blockIdx.x * 32 + ((tid >> 6) << 3) + (lane >> 3);
    bool valid = r < n;

    int beg = 0, end = 0;
    if (valid) { beg = rowptr[r]; end = rowptr[r + 1]; }

    const __half* hp = h + fi;
    auto ld = [&](int src) { return *(const uint4*)(hp + (size_t)src * NFEAT); };

    float a0 = 0.f, a1 = 0.f, a2 = 0.f, a3 = 0.f,
          a4 = 0.f, a5 = 0.f, a6 = 0.f, a7 = 0.f;
    auto addu = [&](uint4 u) {
        float2 f0 = __half22float2(bch(u.x));
        float2 f1 = __half22float2(bch(u.y));
        float2 f2 = __half22float2(bch(u.z));
        float2 f3 = __half22float2(bch(u.w));
        a0 += f0.x; a1 += f0.y; a2 += f1.x; a3 += f1.y;
        a4 += f2.x; a5 += f2.y; a6 += f3.x; a7 += f3.y;
    };

    if (valid) addu(ld(r));
    int j = beg;
    for (; j + 1 < end; j += 2) {
        uint4 u0 = ld(col[j]);
        uint4 u1 = ld(col[j + 1]);
        uint4 s;
        s.x = __builtin_bit_cast(unsigned int, __hadd2(bch(u0.x), bch(u1.x)));
        s.y = __builtin_bit_cast(unsigned int, __hadd2(bch(u0.y), bch(u1.y)));
        s.z = __builtin_bit_cast(unsigned int, __hadd2(bch(u0.z), bch(u1.z)));
        s.w = __builtin_bit_cast(unsigned int, __hadd2(bch(u0.w), bch(u1.w)));
        addu(s);
    }
    if (j < end) addu(ld(col[j]));

    if (!valid) return;
    float di = dinv[r];
    float t0 = fmaxf(bias[fi + 0] + di * a0, 0.f);
    float t1 = fmaxf(bias[fi + 1] + di * a1, 0.f);
    float t2 = fmaxf(bias[fi + 2] + di * a2, 0.f);
    float t3 = fmaxf(bias[fi + 3] + di * a3, 0.f);
    float t4 = fmaxf(bias[fi + 4] + di * a4, 0.f);
    float t5 = fmaxf(bias[fi + 5] + di * a5, 0.f);
    float t6 = fmaxf(bias[fi + 6] + di * a6, 0.f);
    float t7 = fmaxf(bias[fi + 7] + di * a7, 0.f);

    if (!FC) {
        float4 lo = make_float4(t0, t1, t2, t3);
        float4 hi = make_float4(t4, t5, t6, t7);
        float* op = out + (size_t)r * NFEAT + fi;
        *(float4*)op = lo;
        *(float4*)(op + 4) = hi;
    } else {
#pragma unroll
        for (int c = 0; c < 11; ++c) {
            const float* wc = &Wl[fi * 11 + c];
            float p = t0 * wc[0] + t1 * wc[11] + t2 * wc[22] + t3 * wc[33]
                    + t4 * wc[44] + t5 * wc[55] + t6 * wc[66] + t7 * wc[77];
            p += __shfl_xor(p, 1, 64);
            p += __shfl_xor(p, 2, 64);
            p += __shfl_xor(p, 4, 64);
            if (li == 0) out[(size_t)r * 11 + c] = p + Wl[NFEAT * 11 + c];
        }
    }
}

extern "C" void kernel_launch(void* const* d_in, const int* in_sizes, int n_in,
                              void* d_out, int out_size, void* d_ws, size_t ws_size,
                              hipStream_t stream) {
    const float* x   = (const float*)d_in[0];
    const int*   ei  = (const int*)d_in[1];
    const float* W1  = (const float*)d_in[2];
    const float* b1  = (const float*)d_in[3];
    const float* W2  = (const float*)d_in[4];
    const float* b2  = (const float*)d_in[5];
    const float* Wfc = (const float*)d_in[6];
    const float* bfc = (const float*)d_in[7];
    float* out = (float*)d_out;

    const int Fin = 256;
    int N = in_sizes[0] / Fin;      // 100000
    int E = in_sizes[1] / 2;        // 1600000

    char* ws = (char*)d_ws;
    size_t off = 0;
    auto alloc = [&](size_t bytes) { void* p = ws + off; off = (off + bytes + 255) & ~(size_t)255; return p; };
    int*    counts = (int*)   alloc((size_t)N * 4);
    int*    rowptr = (int*)   alloc((size_t)(N + 1) * 4);
    float*  dinv   = (float*) alloc((size_t)N * 4);
    int*    bsums  = (int*)   alloc(64 * 4);
    int*    rank   = (int*)   alloc((size_t)E * 4);
    int*    col    = (int*)   alloc((size_t)E * 4);
    __half* Wt1    = (__half*)alloc((size_t)64 * 256 * 2);
    __half* Wt2    = (__half*)alloc((size_t)64 * 64 * 2);
    __half* A      = (__half*)alloc((size_t)N * NFEAT * 2);  // h buffer (fp16)
    float*  B      = (float*) alloc((size_t)N * NFEAT * 4);  // relu(out1) buffer

    int gE = (E + 255) / 256;       // 6250
    int gb = (N + 127) / 128;       // 782
    int gA = (N + 31) / 32;         // 3125
    int gS = (N * 8 + 255) / 256;   // 3125 (scale, uint4 granules)
    int nb = (N + SCAN_CHUNK - 1) / SCAN_CHUNK;   // 49 <= 64
    int gN = (N + 255) / 256;       // 391

    hipMemsetAsync(counts, 0, (size_t)N * 4, stream);
    k_cvtW<<<(64 * 256 + 255) / 256, 256, 0, stream>>>(W1, Wt1, 256);
    k_cvtW<<<(64 * 64 + 255) / 256, 256, 0, stream>>>(W2, Wt2, 64);

    // FUSED: gemm1 (unscaled) + degree count/rank, 2:1 block interleave
    k_gemm_x<256, false, true><<<gb * 3, 256, 0, stream>>>(
        x, Wt1, nullptr, A, N, ei + E, counts, rank, E);

    // scan phase A + dinv
    k_dinv_scan<<<nb + gN, 256, 0, stream>>>(counts, bsums, dinv, N, nb);
    k_scan_sums<<<1, 64, 0, stream>>>(bsums, nb);
    k_scan_final<<<nb, 256, 0, stream>>>(counts, bsums, rowptr, N);

    // FUSED: CSR placement + deferred h1 *= dinv
    k_build_scale<<<gE + gS, 256, 0, stream>>>(ei, rank, rowptr, col, E, A, dinv, N, gE);

    // layer 1 aggregation: B = relu(b1 + dinv*(h1[r]+sum h1[col]))
    k_aggr<false><<<gA, 256, 0, stream>>>(A, rowptr, col, dinv, b1, nullptr, nullptr, B, N);

    // layer 2: h2 = fp16(dinv*(B@W2)); fused aggr+relu+FC -> out
    k_gemm_x<64, true, false><<<gb, 256, 0, stream>>>(
        B, Wt2, dinv, A, N, nullptr, nullptr, nullptr, 0);
    k_aggr<true><<<gA, 256, 0, stream>>>(A, rowptr, col, dinv, b2, Wfc, bfc, out, N);
}